// Round 9
// baseline (347.512 us; speedup 1.0000x reference)
//
#include <hip/hip_runtime.h>
#include <stdint.h>

typedef unsigned short u16;
typedef unsigned int   u32;
typedef __attribute__((ext_vector_type(8))) short bf16x8;
typedef __attribute__((ext_vector_type(4))) float f32x4;
typedef __attribute__((ext_vector_type(2))) float f32x2;
typedef __attribute__((ext_vector_type(8))) unsigned short u16x8;

constexpr int NUc = 100000;
constexpr int NIc = 100000;
constexpr int Ec  = 500000;
constexpr int Mrows = 100000;
constexpr int NB  = (100000 + 255) / 256;   // 391 scan blocks

__device__ __forceinline__ u16 f2bf(float f) {
  u32 u = __float_as_uint(f);
  u += 0x7fffu + ((u >> 16) & 1u);          // round-to-nearest-even
  return (u16)(u >> 16);
}
__device__ __forceinline__ float bf2f(u16 h) { return __uint_as_float(((u32)h) << 16); }

// ==================== degree histogram + rank (standalone: full machine, latency regime) ====================
__global__ void hist_kernel(const int* __restrict__ e1_dst, const int* __restrict__ e2_dst,
                            int* __restrict__ ideg1, int* __restrict__ ideg2,
                            int* __restrict__ rank1, int* __restrict__ rank2) {
  int i = blockIdx.x * blockDim.x + threadIdx.x;
  const int stride = gridDim.x * blockDim.x;
  for (; i < 2 * Ec; i += stride) {
    if (i < Ec) rank1[i] = atomicAdd(&ideg1[e1_dst[i]], 1);
    else        rank2[i - Ec] = atomicAdd(&ideg2[e2_dst[i - Ec]], 1);
  }
}

// ==================== cast + weight prep (standalone: pure streaming at full BW) ====================
constexpr int PREP_B = 4096;
__global__ void prep_cast(const float* __restrict__ eu, const float* __restrict__ ei,
                          const float* __restrict__ W1s_ui, const float* __restrict__ W1n_ui,
                          const float* __restrict__ W1s_iu, const float* __restrict__ W1n_iu,
                          const float* __restrict__ W2s_ui, const float* __restrict__ W2n_ui,
                          const float* __restrict__ W2s_iu, const float* __restrict__ W2n_iu,
                          u16* __restrict__ ue, u16* __restrict__ ie,
                          u16* __restrict__ Wt1_ui, u16* __restrict__ Wt1_iu,
                          u16* __restrict__ Wt2c_u, u16* __restrict__ Wt2c_i) {
  constexpr int N4 = NUc * 128 / 4;
  constexpr int TOT = 2 * N4 + 262144;
  int i = blockIdx.x * blockDim.x + threadIdx.x;
  const int stride = PREP_B * 256;
  for (int t = i; t < TOT; t += stride) {
    if (t < 2 * N4) {
      const float* src = (t < N4) ? eu : ei;
      u16* dst = (t < N4) ? ue : ie;
      int c = (t < N4) ? t : t - N4;
      f32x4 v = __builtin_nontemporal_load(reinterpret_cast<const f32x4*>(src) + c);
      ushort4 o;
      o.x = f2bf(v.x); o.y = f2bf(v.y); o.z = f2bf(v.z); o.w = f2bf(v.w);
      reinterpret_cast<ushort4*>(dst)[c] = o;   // cached: re-read by gather/gemm
    } else {
      int j = t - 2 * N4;
      if (j < 131072) {                      // Wt1
        const float* Ws = (j < 65536) ? W1s_ui : W1s_iu;
        const float* Wn = (j < 65536) ? W1n_ui : W1n_iu;
        u16* dst = (j < 65536) ? Wt1_ui : Wt1_iu;
        int q = j & 65535;
        int n = q >> 8, k = q & 255;
        dst[q] = f2bf(k < 128 ? Ws[k * 256 + n] : Wn[(k - 128) * 256 + n]);
      } else {                               // Wt2c
        int q = j - 131072;
        int which = q >> 16;                 // 0: A=h1u set, 1: A=h1i set
        int s = q & 65535;
        int c = s >> 8, k = s & 255;
        float v;
        if (which == 0) v = (c < 128) ? W2n_ui[k * 128 + c] : W2s_iu[k * 128 + (c - 128)];
        else            v = (c < 128) ? W2n_iu[k * 128 + c] : W2s_ui[k * 128 + (c - 128)];
        u16* dst = which ? Wt2c_i : Wt2c_u;
        dst[s] = f2bf(v);
      }
    }
  }
}

// ==================== CSR scans ====================
__global__ void block_reduce2(const int* __restrict__ ideg1, const int* __restrict__ ideg2,
                              int* __restrict__ bsum1, int* __restrict__ bsum2, int n) {
  const int* deg = blockIdx.y ? ideg2 : ideg1;
  int* bsum = blockIdx.y ? bsum2 : bsum1;
  __shared__ int s[256];
  int t = threadIdx.x, i = blockIdx.x * 256 + t;
  s[t] = (i < n) ? deg[i] : 0;
  __syncthreads();
  for (int st = 128; st > 0; st >>= 1) { if (t < st) s[t] += s[t + st]; __syncthreads(); }
  if (t == 0) bsum[blockIdx.x] = s[0];
}

__global__ void scan_bsums2(const int* __restrict__ bsum1, const int* __restrict__ bsum2,
                            int* __restrict__ bscan1, int* __restrict__ bscan2, int nb) {
  const int* bsum = blockIdx.x ? bsum2 : bsum1;
  int* bscan = blockIdx.x ? bscan2 : bscan1;
  __shared__ int s[512];
  int t = threadIdx.x;
  int v0 = (t < nb) ? bsum[t] : 0;
  s[t] = v0;
  __syncthreads();
  for (int d = 1; d < 512; d <<= 1) {
    int v = (t >= d) ? s[t - d] : 0;
    __syncthreads();
    s[t] += v;
    __syncthreads();
  }
  if (t < nb) bscan[t] = s[t] - v0;   // exclusive
}

__global__ void scan_blocks2(const int* __restrict__ ideg1, const int* __restrict__ ideg2,
                             const int* __restrict__ bscan1, const int* __restrict__ bscan2,
                             int* __restrict__ off1, int* __restrict__ off2, int n) {
  const int* deg = blockIdx.y ? ideg2 : ideg1;
  const int* bscan = blockIdx.y ? bscan2 : bscan1;
  int* off = blockIdx.y ? off2 : off1;
  __shared__ int s[256];
  int t = threadIdx.x, i = blockIdx.x * 256 + t;
  int d = (i < n) ? deg[i] : 0;
  s[t] = d;
  __syncthreads();
  for (int st = 1; st < 256; st <<= 1) {
    int v = (t >= st) ? s[t - st] : 0;
    __syncthreads();
    s[t] += v;
    __syncthreads();
  }
  if (i < n) off[i] = bscan[blockIdx.x] + s[t] - d;
  if (i == 0) off[n] = Ec;
}

__global__ void fill_csr_kernel(const int* __restrict__ e1_src, const int* __restrict__ e1_dst,
                                const int* __restrict__ e2_src, const int* __restrict__ e2_dst,
                                const int* __restrict__ rank1, const int* __restrict__ rank2,
                                const int* __restrict__ off1, const int* __restrict__ off2,
                                int* __restrict__ csr1, int* __restrict__ csr2) {
  int i = blockIdx.x * blockDim.x + threadIdx.x;
  const int stride = gridDim.x * blockDim.x;
  for (; i < 2 * Ec; i += stride) {
    if (i < Ec) {
      int d = __builtin_nontemporal_load(e1_dst + i);
      int r = __builtin_nontemporal_load(rank1 + i);
      csr1[off1[d] + r] = __builtin_nontemporal_load(e1_src + i);
    } else {
      int e = i - Ec;
      int d = __builtin_nontemporal_load(e2_dst + e);
      int r = __builtin_nontemporal_load(rank2 + e);
      csr2[off2[d] + r] = __builtin_nontemporal_load(e2_src + e);
    }
  }
}

// ==================== block-staged CSR gather ====================
// One block = 64 consecutive dst rows. off-slice + csr-slice staged in LDS (fallback to
// global csr if the block's edge count exceeds CAP). Wave w handles rows w, w+4, ...
// FINAL=0: out bf16 = mean(f[csr])          (aggb, cached — re-read by L1 GEMM)
// FINAL=1: out f32  = bf16(self) + mean(proj[csr])   (nt-stored to d_out)
template<int FINAL>
__global__ __launch_bounds__(256) void gather_blk(
    const u16* __restrict__ fA, const int* __restrict__ offA, const int* __restrict__ csrA,
    const u16* __restrict__ sA, void* __restrict__ outA,
    const u16* __restrict__ fB, const int* __restrict__ offB, const int* __restrict__ csrB,
    const u16* __restrict__ sB, void* __restrict__ outB)
{
  constexpr int ROWS = 64;
  constexpr int CAP  = 1536;
  constexpr int NBLK = (100000 + ROWS - 1) / ROWS;   // 1563
  __shared__ int s_off[ROWS + 1];
  __shared__ int s_csr[CAP];

  const int b = blockIdx.x;
  const u16* f; const int* off; const int* csr; const u16* sf; void* out; int r0;
  if (b < NBLK) { f = fA; off = offA; csr = csrA; sf = sA; out = outA; r0 = b * ROWS; }
  else          { f = fB; off = offB; csr = csrB; sf = sB; out = outB; r0 = (b - NBLK) * ROWS; }

  const int tid = threadIdx.x;
  if (tid <= ROWS) s_off[tid] = off[min(r0 + tid, 100000)];
  __syncthreads();
  const int j0 = s_off[0];
  const int nE = s_off[ROWS] - j0;
  const bool inLds = (nE <= CAP);
  if (inLds) {
    for (int j = tid; j < nE; j += 256) s_csr[j] = csr[j0 + j];
  }
  __syncthreads();

  const int w = tid >> 6, lane = tid & 63;
  const int colb = lane << 1;
  for (int rr = w; rr < ROWS; rr += 4) {
    const int r = r0 + rr;
    if (r >= 100000) break;
    const int a0 = s_off[rr], a1 = s_off[rr + 1];
    float ax = 0.f, ay = 0.f;
    int t = a0;
    if (inLds) {
      const int base = a0 - j0;
      int tl = base;
      const int el = a1 - j0;
      for (; tl + 4 <= el; tl += 4) {
        int s0 = s_csr[tl], s1 = s_csr[tl + 1], s2 = s_csr[tl + 2], s3 = s_csr[tl + 3];
        u32 v0 = *reinterpret_cast<const u32*>(f + (size_t)s0 * 128 + colb);
        u32 v1 = *reinterpret_cast<const u32*>(f + (size_t)s1 * 128 + colb);
        u32 v2 = *reinterpret_cast<const u32*>(f + (size_t)s2 * 128 + colb);
        u32 v3 = *reinterpret_cast<const u32*>(f + (size_t)s3 * 128 + colb);
        ax += __uint_as_float(v0 << 16) + __uint_as_float(v1 << 16)
            + __uint_as_float(v2 << 16) + __uint_as_float(v3 << 16);
        ay += __uint_as_float(v0 & 0xffff0000u) + __uint_as_float(v1 & 0xffff0000u)
            + __uint_as_float(v2 & 0xffff0000u) + __uint_as_float(v3 & 0xffff0000u);
      }
      for (; tl < el; ++tl) {
        int s0 = s_csr[tl];
        u32 v0 = *reinterpret_cast<const u32*>(f + (size_t)s0 * 128 + colb);
        ax += __uint_as_float(v0 << 16);
        ay += __uint_as_float(v0 & 0xffff0000u);
      }
    } else {
      for (; t + 4 <= a1; t += 4) {
        int s0 = csr[t], s1 = csr[t + 1], s2 = csr[t + 2], s3 = csr[t + 3];
        u32 v0 = *reinterpret_cast<const u32*>(f + (size_t)s0 * 128 + colb);
        u32 v1 = *reinterpret_cast<const u32*>(f + (size_t)s1 * 128 + colb);
        u32 v2 = *reinterpret_cast<const u32*>(f + (size_t)s2 * 128 + colb);
        u32 v3 = *reinterpret_cast<const u32*>(f + (size_t)s3 * 128 + colb);
        ax += __uint_as_float(v0 << 16) + __uint_as_float(v1 << 16)
            + __uint_as_float(v2 << 16) + __uint_as_float(v3 << 16);
        ay += __uint_as_float(v0 & 0xffff0000u) + __uint_as_float(v1 & 0xffff0000u)
            + __uint_as_float(v2 & 0xffff0000u) + __uint_as_float(v3 & 0xffff0000u);
      }
      for (; t < a1; ++t) {
        int s0 = csr[t];
        u32 v0 = *reinterpret_cast<const u32*>(f + (size_t)s0 * 128 + colb);
        ax += __uint_as_float(v0 << 16);
        ay += __uint_as_float(v0 & 0xffff0000u);
      }
    }
    float rs = 1.0f / fmaxf((float)(a1 - a0), 1.0f);
    if (FINAL) {
      u32 sv = __builtin_nontemporal_load(
          reinterpret_cast<const u32*>(sf + (size_t)r * 128 + colb));
      f32x2 o;
      o.x = ax * rs + __uint_as_float(sv << 16);
      o.y = ay * rs + __uint_as_float(sv & 0xffff0000u);
      __builtin_nontemporal_store(o, reinterpret_cast<f32x2*>((float*)out + (size_t)r * 128 + colb));
    } else {
      u32 o = (u32)f2bf(ax * rs) | ((u32)f2bf(ay * rs) << 16);
      *reinterpret_cast<u32*>((u16*)out + (size_t)r * 128 + colb) = o;
    }
  }
}

// ==================== MFMA GEMM (256 thr, BMxBN=128x128, z-batched) ====================
// EPI 0: h1 = leaky([X;S]@W1 + b1), bf16 out [M][256], grid.y = col-tile
// EPI 1: dual out: y=0 -> out0 = A@Wn (proj, cached); y=1 -> out1 = A@Ws + bias (nt)
__device__ __forceinline__ void glds16(const void* g, void* l) {
  __builtin_amdgcn_global_load_lds((const __attribute__((address_space(1))) void*)g,
                                   (__attribute__((address_space(3))) void*)l, 16, 0, 0);
}

template<int NTAB, int EPI, int AST>
__global__ __launch_bounds__(256) void mfma_gemm2(
    const u16* __restrict__ A0a, const u16* __restrict__ A1a, const u16* __restrict__ Bta,
    const float* __restrict__ biasa, u16* __restrict__ out0a, u16* __restrict__ out1a,
    const u16* __restrict__ A0b, const u16* __restrict__ A1b, const u16* __restrict__ Btb,
    const float* __restrict__ biasb, u16* __restrict__ out0b, u16* __restrict__ out1b,
    int M)
{
  constexpr int K = 256, BK = 32, BM = 128;
  __shared__ __align__(16) u16 smem[8192];   // As [0,4096), Bs [4096,8192); epi slab reuses all
  u16* As = smem;
  u16* Bs = smem + 4096;

  const bool zb = (blockIdx.z != 0);
  const u16* A0 = zb ? A0b : A0a;
  const u16* A1 = zb ? A1b : A1a;
  const u16* Bt = zb ? Btb : Bta;
  const float* bias = zb ? biasb : biasa;

  const int tid  = threadIdx.x;
  const int lane = tid & 63;
  const int w    = tid >> 6;
  const int wr   = w >> 1, wc = w & 1;
  const int gr0  = blockIdx.x * BM;
  const int gc0  = blockIdx.y * BM;

  f32x4 acc[4][4];
  #pragma unroll
  for (int m = 0; m < 4; ++m)
    #pragma unroll
    for (int n = 0; n < 4; ++n) acc[m][n] = (f32x4){0.f, 0.f, 0.f, 0.f};

  const int srow  = lane >> 2;   // 0..15 within a 16-row chunk
  const int sslot = lane & 3;    // 16B slot within 64B row

  for (int kt = 0; kt < K; kt += BK) {
    const u16* At = (NTAB == 2 && kt >= 128) ? A1 : A0;
    const int kbase = (NTAB == 2) ? (kt & 127) : kt;
    #pragma unroll
    for (int c = 0; c < 2; ++c) {
      int rl = w * 32 + c * 16 + srow;                 // LDS-local row 0..127
      int swz = (sslot ^ ((rl >> 1) & 3)) << 3;        // swizzled k-slot (elements)
      int grow = gr0 + rl; grow = grow < M ? grow : M - 1;
      glds16(At + (size_t)grow * AST + kbase + swz, As + (size_t)(w * 32 + c * 16) * BK);
      glds16(Bt + (size_t)(gc0 + rl) * K + kt + swz, Bs + (size_t)(w * 32 + c * 16) * BK);
    }
    __syncthreads();

    bf16x8 af[4], bfr[4];
    #pragma unroll
    for (int m = 0; m < 4; ++m) {
      int row = wr * 64 + m * 16 + (lane & 15);
      int idx = (row << 5) + ((((lane >> 4) ^ ((row >> 1) & 3))) << 3);
      af[m] = *reinterpret_cast<const bf16x8*>(As + idx);
    }
    #pragma unroll
    for (int n = 0; n < 4; ++n) {
      int row = wc * 64 + n * 16 + (lane & 15);
      int idx = (row << 5) + ((((lane >> 4) ^ ((row >> 1) & 3))) << 3);
      bfr[n] = *reinterpret_cast<const bf16x8*>(Bs + idx);
    }
    #pragma unroll
    for (int m = 0; m < 4; ++m)
      #pragma unroll
      for (int n = 0; n < 4; ++n)
        acc[m][n] = __builtin_amdgcn_mfma_f32_16x16x32_bf16(af[m], bfr[n], acc[m][n], 0, 0, 0);
    __syncthreads();
  }

  // ---- epilogue: acc -> LDS slab (64 rows x 128 cols bf16) -> coalesced 16B stores ----
  u16* outp;
  if (EPI == 0) outp = zb ? out0b : out0a;
  else          outp = (blockIdx.y == 0) ? (zb ? out0b : out0a) : (zb ? out1b : out1a);
  const bool useBias = (EPI == 0) || (blockIdx.y == 1);
  const bool ntStore = (EPI == 1) && (blockIdx.y == 1);   // self_* : read once, streaming

  const int cLane = lane & 15;
  const int rGrp  = (lane >> 4) << 2;
  for (int s = 0; s < 2; ++s) {
    if (wr == s) {
      #pragma unroll
      for (int n = 0; n < 4; ++n) {
        int lc = wc * 64 + n * 16 + cLane;             // 0..127 local col
        float b = 0.f;
        if (useBias) b = (EPI == 0) ? bias[gc0 + lc] : bias[lc];
        #pragma unroll
        for (int m = 0; m < 4; ++m) {
          int lr = m * 16 + rGrp;
          #pragma unroll
          for (int r = 0; r < 4; ++r) {
            float v = acc[m][n][r] + b;
            if (EPI == 0) v = (v >= 0.f) ? v : 0.01f * v;
            smem[(lr + r) * 128 + lc] = f2bf(v);
          }
        }
      }
    }
    __syncthreads();
    #pragma unroll
    for (int pass = 0; pass < 4; ++pass) {
      int chunk = pass * 256 + tid;
      int row = chunk >> 4, c8 = chunk & 15;
      int G = gr0 + s * 64 + row;
      if (G < M) {
        u16x8 v = *reinterpret_cast<const u16x8*>(smem + row * 128 + c8 * 8);
        if (EPI == 0)
          *reinterpret_cast<u16x8*>(outp + (size_t)G * 256 + gc0 + c8 * 8) = v;
        else if (ntStore)
          __builtin_nontemporal_store(v, reinterpret_cast<u16x8*>(outp + (size_t)G * 128 + c8 * 8));
        else
          *reinterpret_cast<u16x8*>(outp + (size_t)G * 128 + c8 * 8) = v;
      }
    }
    if (s == 0) __syncthreads();
  }
}

// ==================== launch ====================
extern "C" void kernel_launch(void* const* d_in, const int* in_sizes, int n_in,
                              void* d_out, int out_size, void* d_ws, size_t ws_size,
                              hipStream_t stream) {
  const float* emb_user    = (const float*)d_in[0];
  const float* emb_item    = (const float*)d_in[1];
  const float* W1_self_ui  = (const float*)d_in[2];
  const float* W1_neigh_ui = (const float*)d_in[3];
  const float* b1_ui       = (const float*)d_in[4];
  const float* W1_self_iu  = (const float*)d_in[5];
  const float* W1_neigh_iu = (const float*)d_in[6];
  const float* b1_iu       = (const float*)d_in[7];
  const float* W2_self_ui  = (const float*)d_in[8];
  const float* W2_neigh_ui = (const float*)d_in[9];
  const float* b2_ui       = (const float*)d_in[10];
  const float* W2_self_iu  = (const float*)d_in[11];
  const float* W2_neigh_iu = (const float*)d_in[12];
  const float* b2_iu       = (const float*)d_in[13];
  const int* e1_src = (const int*)d_in[14];
  const int* e1_dst = (const int*)d_in[15];
  const int* e2_src = (const int*)d_in[16];
  const int* e2_dst = (const int*)d_in[17];

  // ---- workspace ----
  u16* p16 = (u16*)d_ws;
  u16* ue     = p16; p16 += (size_t)NUc * 128;
  u16* ie     = p16; p16 += (size_t)NIc * 128;
  u16* h1i    = p16; p16 += (size_t)NIc * 256;
  u16* h1u    = p16; p16 += (size_t)NUc * 256;
  u16* aggb_i = p16; p16 += (size_t)NIc * 128;   // reused as proj_u2i after L1 GEMM
  u16* aggb_u = p16; p16 += (size_t)NUc * 128;   // reused as self_u after L1 GEMM
  u16* proj_i2u = p16; p16 += (size_t)NIc * 128;
  u16* self_i   = p16; p16 += (size_t)NIc * 128;
  u16* Wt1_ui  = p16; p16 += 256 * 256;
  u16* Wt1_iu  = p16; p16 += 256 * 256;
  u16* Wt2c_u  = p16; p16 += 256 * 256;
  u16* Wt2c_i  = p16; p16 += 256 * 256;
  u16* proj_u2i = aggb_i;   // alias (sequential reuse)
  u16* self_u   = aggb_u;   // alias
  int* ip    = (int*)p16;
  int* ideg1 = ip;  ip += NIc;
  int* ideg2 = ip;  ip += NUc;
  int* off1  = ip;  ip += NIc + 1;
  int* off2  = ip;  ip += NUc + 1;
  int* rank1 = ip;  ip += Ec;
  int* rank2 = ip;  ip += Ec;
  int* csr1  = ip;  ip += Ec;
  int* csr2  = ip;  ip += Ec;
  int* bsum1 = ip;  ip += 512;
  int* bscan1= ip;  ip += 512;
  int* bsum2 = ip;  ip += 512;
  int* bscan2= ip;  ip += 512;

  float* h2_user = (float*)d_out;
  float* h2_item = h2_user + (size_t)NUc * 128;

  dim3 blk(256);
  const int gatherBlocks = 2 * ((100000 + 63) / 64);   // 3126
  dim3 gemmGrid(782, 2, 2);

  // ---- CSR build + prep (separate kernels: each runs in its own regime) ----
  hipMemsetAsync(ideg1, 0, sizeof(int) * (size_t)(NIc + NUc), stream);
  hist_kernel<<<1024, blk, 0, stream>>>(e1_dst, e2_dst, ideg1, ideg2, rank1, rank2);
  prep_cast<<<PREP_B, blk, 0, stream>>>(
      emb_user, emb_item,
      W1_self_ui, W1_neigh_ui, W1_self_iu, W1_neigh_iu,
      W2_self_ui, W2_neigh_ui, W2_self_iu, W2_neigh_iu,
      ue, ie, Wt1_ui, Wt1_iu, Wt2c_u, Wt2c_i);
  block_reduce2<<<dim3(NB, 2), blk, 0, stream>>>(ideg1, ideg2, bsum1, bsum2, NIc);
  scan_bsums2<<<2, 512, 0, stream>>>(bsum1, bsum2, bscan1, bscan2, NB);
  scan_blocks2<<<dim3(NB, 2), blk, 0, stream>>>(ideg1, ideg2, bscan1, bscan2, off1, off2, NIc);
  fill_csr_kernel<<<1024, blk, 0, stream>>>(e1_src, e1_dst, e2_src, e2_dst,
                                            rank1, rank2, off1, off2, csr1, csr2);

  // ---- layer 1: block-staged gather + fused GEMM -> h1 (bf16) ----
  gather_blk<0><<<gatherBlocks, blk, 0, stream>>>(
      ue, off1, csr1, nullptr, aggb_i,
      ie, off2, csr2, nullptr, aggb_u);
  mfma_gemm2<2, 0, 128><<<gemmGrid, blk, 0, stream>>>(
      ie, aggb_i, Wt1_ui, b1_ui, h1i, nullptr,
      ue, aggb_u, Wt1_iu, b1_iu, h1u, nullptr, Mrows);

  // ---- layer 2: combined dual-output GEMM (proj + self), h1 read once ----
  mfma_gemm2<1, 1, 256><<<gemmGrid, blk, 0, stream>>>(
      h1u, nullptr, Wt2c_u, b2_iu, proj_u2i, self_u,
      h1i, nullptr, Wt2c_i, b2_ui, proj_i2u, self_i, Mrows);

  // ---- layer 2: block-staged gather + final add -> f32 outputs ----
  gather_blk<1><<<gatherBlocks, blk, 0, stream>>>(
      proj_u2i, off1, csr1, self_i, h2_item,
      proj_i2u, off2, csr2, self_u, h2_user);
}

// Round 10
// 342.080 us; speedup vs baseline: 1.0159x; 1.0159x over previous
//
#include <hip/hip_runtime.h>
#include <stdint.h>

typedef unsigned short u16;
typedef unsigned int   u32;
typedef __attribute__((ext_vector_type(8))) short bf16x8;
typedef __attribute__((ext_vector_type(4))) float f32x4;
typedef __attribute__((ext_vector_type(2))) float f32x2;
typedef __attribute__((ext_vector_type(8))) unsigned short u16x8;

constexpr int NUc = 100000;
constexpr int NIc = 100000;
constexpr int Ec  = 500000;
constexpr int Mrows = 100000;
constexpr int NB  = (100000 + 255) / 256;   // 391 scan blocks

__device__ __forceinline__ u16 f2bf(float f) {
  u32 u = __float_as_uint(f);
  u += 0x7fffu + ((u >> 16) & 1u);          // round-to-nearest-even
  return (u16)(u >> 16);
}

// ==================== degree histogram + rank ====================
__global__ void hist_kernel(const int* __restrict__ e1_dst, const int* __restrict__ e2_dst,
                            int* __restrict__ ideg1, int* __restrict__ ideg2,
                            int* __restrict__ rank1, int* __restrict__ rank2) {
  int i = blockIdx.x * blockDim.x + threadIdx.x;
  const int stride = gridDim.x * blockDim.x;
  for (; i < 2 * Ec; i += stride) {
    if (i < Ec) rank1[i] = atomicAdd(&ideg1[e1_dst[i]], 1);
    else        rank2[i - Ec] = atomicAdd(&ideg2[e2_dst[i - Ec]], 1);
  }
}

// ==================== cast + weight prep ====================
constexpr int PREP_B = 4096;
__global__ void prep_cast(const float* __restrict__ eu, const float* __restrict__ ei,
                          const float* __restrict__ W1s_ui, const float* __restrict__ W1n_ui,
                          const float* __restrict__ W1s_iu, const float* __restrict__ W1n_iu,
                          const float* __restrict__ W2s_ui, const float* __restrict__ W2n_ui,
                          const float* __restrict__ W2s_iu, const float* __restrict__ W2n_iu,
                          u16* __restrict__ ue, u16* __restrict__ ie,
                          u16* __restrict__ Wt1_ui, u16* __restrict__ Wt1_iu,
                          u16* __restrict__ Wt2c_u, u16* __restrict__ Wt2c_i) {
  constexpr int N4 = NUc * 128 / 4;
  constexpr int TOT = 2 * N4 + 262144;
  int i = blockIdx.x * blockDim.x + threadIdx.x;
  const int stride = PREP_B * 256;
  for (int t = i; t < TOT; t += stride) {
    if (t < 2 * N4) {
      const float* src = (t < N4) ? eu : ei;
      u16* dst = (t < N4) ? ue : ie;
      int c = (t < N4) ? t : t - N4;
      f32x4 v = __builtin_nontemporal_load(reinterpret_cast<const f32x4*>(src) + c);
      ushort4 o;
      o.x = f2bf(v.x); o.y = f2bf(v.y); o.z = f2bf(v.z); o.w = f2bf(v.w);
      reinterpret_cast<ushort4*>(dst)[c] = o;   // cached: re-read by gather/gemm
    } else {
      int j = t - 2 * N4;
      if (j < 131072) {                      // Wt1 [256 outcol][256 k]
        const float* Ws = (j < 65536) ? W1s_ui : W1s_iu;
        const float* Wn = (j < 65536) ? W1n_ui : W1n_iu;
        u16* dst = (j < 65536) ? Wt1_ui : Wt1_iu;
        int q = j & 65535;
        int n = q >> 8, k = q & 255;
        dst[q] = f2bf(k < 128 ? Ws[k * 256 + n] : Wn[(k - 128) * 256 + n]);
      } else {                               // Wt2c [256 outcol][256 k]
        int q = j - 131072;
        int which = q >> 16;                 // 0: applied to h1u, 1: applied to h1i
        int s = q & 65535;
        int c = s >> 8, k = s & 255;
        float v;
        if (which == 0) v = (c < 128) ? W2n_ui[k * 128 + c] : W2s_iu[k * 128 + (c - 128)];
        else            v = (c < 128) ? W2n_iu[k * 128 + c] : W2s_ui[k * 128 + (c - 128)];
        u16* dst = which ? Wt2c_i : Wt2c_u;
        dst[s] = f2bf(v);
      }
    }
  }
}

// ==================== CSR scans ====================
__global__ void block_reduce2(const int* __restrict__ ideg1, const int* __restrict__ ideg2,
                              int* __restrict__ bsum1, int* __restrict__ bsum2, int n) {
  const int* deg = blockIdx.y ? ideg2 : ideg1;
  int* bsum = blockIdx.y ? bsum2 : bsum1;
  __shared__ int s[256];
  int t = threadIdx.x, i = blockIdx.x * 256 + t;
  s[t] = (i < n) ? deg[i] : 0;
  __syncthreads();
  for (int st = 128; st > 0; st >>= 1) { if (t < st) s[t] += s[t + st]; __syncthreads(); }
  if (t == 0) bsum[blockIdx.x] = s[0];
}

__global__ void scan_bsums2(const int* __restrict__ bsum1, const int* __restrict__ bsum2,
                            int* __restrict__ bscan1, int* __restrict__ bscan2, int nb) {
  const int* bsum = blockIdx.x ? bsum2 : bsum1;
  int* bscan = blockIdx.x ? bscan2 : bscan1;
  __shared__ int s[512];
  int t = threadIdx.x;
  int v0 = (t < nb) ? bsum[t] : 0;
  s[t] = v0;
  __syncthreads();
  for (int d = 1; d < 512; d <<= 1) {
    int v = (t >= d) ? s[t - d] : 0;
    __syncthreads();
    s[t] += v;
    __syncthreads();
  }
  if (t < nb) bscan[t] = s[t] - v0;   // exclusive
}

__global__ void scan_blocks2(const int* __restrict__ ideg1, const int* __restrict__ ideg2,
                             const int* __restrict__ bscan1, const int* __restrict__ bscan2,
                             int* __restrict__ off1, int* __restrict__ off2, int n) {
  const int* deg = blockIdx.y ? ideg2 : ideg1;
  const int* bscan = blockIdx.y ? bscan2 : bscan1;
  int* off = blockIdx.y ? off2 : off1;
  __shared__ int s[256];
  int t = threadIdx.x, i = blockIdx.x * 256 + t;
  int d = (i < n) ? deg[i] : 0;
  s[t] = d;
  __syncthreads();
  for (int st = 1; st < 256; st <<= 1) {
    int v = (t >= st) ? s[t - st] : 0;
    __syncthreads();
    s[t] += v;
    __syncthreads();
  }
  if (i < n) off[i] = bscan[blockIdx.x] + s[t] - d;
  if (i == 0) off[n] = Ec;
}

__global__ void fill_csr_kernel(const int* __restrict__ e1_src, const int* __restrict__ e1_dst,
                                const int* __restrict__ e2_src, const int* __restrict__ e2_dst,
                                const int* __restrict__ rank1, const int* __restrict__ rank2,
                                const int* __restrict__ off1, const int* __restrict__ off2,
                                int* __restrict__ csr1, int* __restrict__ csr2) {
  int i = blockIdx.x * blockDim.x + threadIdx.x;
  const int stride = gridDim.x * blockDim.x;
  for (; i < 2 * Ec; i += stride) {
    if (i < Ec) {
      int d = __builtin_nontemporal_load(e1_dst + i);
      int r = __builtin_nontemporal_load(rank1 + i);
      csr1[off1[d] + r] = __builtin_nontemporal_load(e1_src + i);
    } else {
      int e = i - Ec;
      int d = __builtin_nontemporal_load(e2_dst + e);
      int r = __builtin_nontemporal_load(rank2 + e);
      csr2[off2[d] + r] = __builtin_nontemporal_load(e2_src + e);
    }
  }
}

// ==================== block-staged CSR gather (unchanged from R8/R9) ====================
template<int FINAL>
__global__ __launch_bounds__(256) void gather_blk(
    const u16* __restrict__ fA, const int* __restrict__ offA, const int* __restrict__ csrA,
    const u16* __restrict__ sA, void* __restrict__ outA,
    const u16* __restrict__ fB, const int* __restrict__ offB, const int* __restrict__ csrB,
    const u16* __restrict__ sB, void* __restrict__ outB)
{
  constexpr int ROWS = 64;
  constexpr int CAP  = 1536;
  constexpr int NBLK = (100000 + ROWS - 1) / ROWS;   // 1563
  __shared__ int s_off[ROWS + 1];
  __shared__ int s_csr[CAP];

  const int b = blockIdx.x;
  const u16* f; const int* off; const int* csr; const u16* sf; void* out; int r0;
  if (b < NBLK) { f = fA; off = offA; csr = csrA; sf = sA; out = outA; r0 = b * ROWS; }
  else          { f = fB; off = offB; csr = csrB; sf = sB; out = outB; r0 = (b - NBLK) * ROWS; }

  const int tid = threadIdx.x;
  if (tid <= ROWS) s_off[tid] = off[min(r0 + tid, 100000)];
  __syncthreads();
  const int j0 = s_off[0];
  const int nE = s_off[ROWS] - j0;
  const bool inLds = (nE <= CAP);
  if (inLds) {
    for (int j = tid; j < nE; j += 256) s_csr[j] = csr[j0 + j];
  }
  __syncthreads();

  const int w = tid >> 6, lane = tid & 63;
  const int colb = lane << 1;
  for (int rr = w; rr < ROWS; rr += 4) {
    const int r = r0 + rr;
    if (r >= 100000) break;
    const int a0 = s_off[rr], a1 = s_off[rr + 1];
    float ax = 0.f, ay = 0.f;
    if (inLds) {
      int tl = a0 - j0;
      const int el = a1 - j0;
      for (; tl + 4 <= el; tl += 4) {
        int s0 = s_csr[tl], s1 = s_csr[tl + 1], s2 = s_csr[tl + 2], s3 = s_csr[tl + 3];
        u32 v0 = *reinterpret_cast<const u32*>(f + (size_t)s0 * 128 + colb);
        u32 v1 = *reinterpret_cast<const u32*>(f + (size_t)s1 * 128 + colb);
        u32 v2 = *reinterpret_cast<const u32*>(f + (size_t)s2 * 128 + colb);
        u32 v3 = *reinterpret_cast<const u32*>(f + (size_t)s3 * 128 + colb);
        ax += __uint_as_float(v0 << 16) + __uint_as_float(v1 << 16)
            + __uint_as_float(v2 << 16) + __uint_as_float(v3 << 16);
        ay += __uint_as_float(v0 & 0xffff0000u) + __uint_as_float(v1 & 0xffff0000u)
            + __uint_as_float(v2 & 0xffff0000u) + __uint_as_float(v3 & 0xffff0000u);
      }
      for (; tl < el; ++tl) {
        int s0 = s_csr[tl];
        u32 v0 = *reinterpret_cast<const u32*>(f + (size_t)s0 * 128 + colb);
        ax += __uint_as_float(v0 << 16);
        ay += __uint_as_float(v0 & 0xffff0000u);
      }
    } else {
      int t = a0;
      for (; t + 4 <= a1; t += 4) {
        int s0 = csr[t], s1 = csr[t + 1], s2 = csr[t + 2], s3 = csr[t + 3];
        u32 v0 = *reinterpret_cast<const u32*>(f + (size_t)s0 * 128 + colb);
        u32 v1 = *reinterpret_cast<const u32*>(f + (size_t)s1 * 128 + colb);
        u32 v2 = *reinterpret_cast<const u32*>(f + (size_t)s2 * 128 + colb);
        u32 v3 = *reinterpret_cast<const u32*>(f + (size_t)s3 * 128 + colb);
        ax += __uint_as_float(v0 << 16) + __uint_as_float(v1 << 16)
            + __uint_as_float(v2 << 16) + __uint_as_float(v3 << 16);
        ay += __uint_as_float(v0 & 0xffff0000u) + __uint_as_float(v1 & 0xffff0000u)
            + __uint_as_float(v2 & 0xffff0000u) + __uint_as_float(v3 & 0xffff0000u);
      }
      for (; t < a1; ++t) {
        int s0 = csr[t];
        u32 v0 = *reinterpret_cast<const u32*>(f + (size_t)s0 * 128 + colb);
        ax += __uint_as_float(v0 << 16);
        ay += __uint_as_float(v0 & 0xffff0000u);
      }
    }
    float rs = 1.0f / fmaxf((float)(a1 - a0), 1.0f);
    if (FINAL) {
      u32 sv = __builtin_nontemporal_load(
          reinterpret_cast<const u32*>(sf + (size_t)r * 128 + colb));
      f32x2 o;
      o.x = ax * rs + __uint_as_float(sv << 16);
      o.y = ay * rs + __uint_as_float(sv & 0xffff0000u);
      __builtin_nontemporal_store(o, reinterpret_cast<f32x2*>((float*)out + (size_t)r * 128 + colb));
    } else {
      u32 o = (u32)f2bf(ax * rs) | ((u32)f2bf(ay * rs) << 16);
      *reinterpret_cast<u32*>((u16*)out + (size_t)r * 128 + colb) = o;
    }
  }
}

// ==================== FUSED layer1+layer2 GEMM ====================
// Per 64-row tile (z picks ntype instance):
//   phase 1: h1 = leaky([X;S] @ W1 + b1)   (acc regs; A staged ONCE)
//   phase 2: h1 -> LDS slab (bf16, granule-XOR swizzled)
//   phase 3: [proj|self] = slab @ W2c (+b2 on self half)
//   phase 4: slab epilogue -> proj (cached) / self (nt)
// h1 never touches HBM.
__device__ __forceinline__ void glds16(const void* g, void* l) {
  __builtin_amdgcn_global_load_lds((const __attribute__((address_space(1))) void*)g,
                                   (__attribute__((address_space(3))) void*)l, 16, 0, 0);
}

__global__ __launch_bounds__(256) void fused_gemm(
    const u16* __restrict__ Xa, const u16* __restrict__ Sa,
    const u16* __restrict__ W1a, const float* __restrict__ b1a,
    const u16* __restrict__ W2a, const float* __restrict__ b2a,
    u16* __restrict__ proja, u16* __restrict__ selfa,
    const u16* __restrict__ Xb, const u16* __restrict__ Sb,
    const u16* __restrict__ W1b, const float* __restrict__ b1b,
    const u16* __restrict__ W2b, const float* __restrict__ b2b,
    u16* __restrict__ projb, u16* __restrict__ selfb,
    int M)
{
  constexpr int K = 256, BK = 32, BM = 64;
  __shared__ __align__(16) u16 As[BM * BK];       // 4 KB
  __shared__ __align__(16) u16 Bs[256 * BK];      // 16 KB
  __shared__ __align__(16) u16 slab[BM * 256];    // 32 KB

  const bool zb = (blockIdx.z != 0);
  const u16* X   = zb ? Xb : Xa;
  const u16* S   = zb ? Sb : Sa;
  const u16* W1  = zb ? W1b : W1a;
  const float* b1 = zb ? b1b : b1a;
  const u16* W2  = zb ? W2b : W2a;
  const float* b2 = zb ? b2b : b2a;
  u16* proj  = zb ? projb : proja;
  u16* selfp = zb ? selfb : selfa;

  const int tid  = threadIdx.x;
  const int lane = tid & 63;
  const int w    = tid >> 6;           // wave 0..3 -> col-tile w*64
  const int gr0  = blockIdx.x * BM;
  const int rl   = tid >> 2;           // stage row 0..63
  const int sslot = tid & 3;           // stage 16B slot

  f32x4 acc[4][4];
  #pragma unroll
  for (int m = 0; m < 4; ++m)
    #pragma unroll
    for (int n = 0; n < 4; ++n) acc[m][n] = (f32x4){0.f, 0.f, 0.f, 0.f};

  // ---- phase 1: h1 tile ----
  for (int kt = 0; kt < K; kt += BK) {
    const u16* At = (kt >= 128) ? S : X;
    const int kbase = kt & 127;
    {
      int swz = (sslot ^ ((rl >> 1) & 3)) << 3;
      int grow = gr0 + rl; grow = grow < M ? grow : M - 1;
      glds16(At + (size_t)grow * 128 + kbase + swz, As + (size_t)(w * 16) * BK);
    }
    #pragma unroll
    for (int h = 0; h < 4; ++h) {
      int rb = h * 64 + rl;
      int swz = (sslot ^ ((rb >> 1) & 3)) << 3;
      glds16(W1 + (size_t)rb * K + kt + swz, Bs + (size_t)(h * 64 + w * 16) * BK);
    }
    __syncthreads();

    bf16x8 af[4], bfr[4];
    #pragma unroll
    for (int m = 0; m < 4; ++m) {
      int row = m * 16 + (lane & 15);
      int idx = (row << 5) + ((((lane >> 4) ^ ((row >> 1) & 3))) << 3);
      af[m] = *reinterpret_cast<const bf16x8*>(As + idx);
    }
    #pragma unroll
    for (int n = 0; n < 4; ++n) {
      int row = w * 64 + n * 16 + (lane & 15);
      int idx = (row << 5) + ((((lane >> 4) ^ ((row >> 1) & 3))) << 3);
      bfr[n] = *reinterpret_cast<const bf16x8*>(Bs + idx);
    }
    #pragma unroll
    for (int m = 0; m < 4; ++m)
      #pragma unroll
      for (int n = 0; n < 4; ++n)
        acc[m][n] = __builtin_amdgcn_mfma_f32_16x16x32_bf16(af[m], bfr[n], acc[m][n], 0, 0, 0);
    __syncthreads();
  }

  // ---- phase 2: leaky(h1 + b1) -> slab (granule-swizzled bf16) ----
  #pragma unroll
  for (int n = 0; n < 4; ++n) {
    int c = w * 64 + n * 16 + (lane & 15);
    float b = b1[c];
    #pragma unroll
    for (int m = 0; m < 4; ++m) {
      #pragma unroll
      for (int r = 0; r < 4; ++r) {
        int row = m * 16 + ((lane >> 4) << 2) + r;
        float v = acc[m][n][r] + b;
        v = (v >= 0.f) ? v : 0.01f * v;
        int g = (c >> 3) ^ (row & 7);
        slab[row * 256 + g * 8 + (c & 7)] = f2bf(v);
        acc[m][n][r] = 0.f;
      }
    }
  }
  __syncthreads();

  // ---- phase 3: [proj|self] = slab @ W2c ----
  for (int kt = 0; kt < K; kt += BK) {
    #pragma unroll
    for (int h = 0; h < 4; ++h) {
      int rb = h * 64 + rl;
      int swz = (sslot ^ ((rb >> 1) & 3)) << 3;
      glds16(W2 + (size_t)rb * K + kt + swz, Bs + (size_t)(h * 64 + w * 16) * BK);
    }
    __syncthreads();

    bf16x8 af[4], bfr[4];
    #pragma unroll
    for (int m = 0; m < 4; ++m) {
      int row = m * 16 + (lane & 15);
      int g = ((kt >> 3) + (lane >> 4)) ^ (row & 7);
      af[m] = *reinterpret_cast<const bf16x8*>(slab + row * 256 + g * 8);
    }
    #pragma unroll
    for (int n = 0; n < 4; ++n) {
      int row = w * 64 + n * 16 + (lane & 15);
      int idx = (row << 5) + ((((lane >> 4) ^ ((row >> 1) & 3))) << 3);
      bfr[n] = *reinterpret_cast<const bf16x8*>(Bs + idx);
    }
    #pragma unroll
    for (int m = 0; m < 4; ++m)
      #pragma unroll
      for (int n = 0; n < 4; ++n)
        acc[m][n] = __builtin_amdgcn_mfma_f32_16x16x32_bf16(af[m], bfr[n], acc[m][n], 0, 0, 0);
    __syncthreads();
  }

  // ---- phase 4: epilogue via slab ----
  #pragma unroll
  for (int n = 0; n < 4; ++n) {
    int c = w * 64 + n * 16 + (lane & 15);
    float b = (c >= 128) ? b2[c - 128] : 0.f;
    #pragma unroll
    for (int m = 0; m < 4; ++m) {
      #pragma unroll
      for (int r = 0; r < 4; ++r) {
        int row = m * 16 + ((lane >> 4) << 2) + r;
        int g = (c >> 3) ^ (row & 7);
        slab[row * 256 + g * 8 + (c & 7)] = f2bf(acc[m][n][r] + b);
      }
    }
  }
  __syncthreads();
  #pragma unroll
  for (int p = 0; p < 8; ++p) {
    int chunk = p * 256 + tid;
    int row = chunk >> 5;            // 0..63
    int gg  = chunk & 31;            // output granule (8 cols)
    int G = gr0 + row;
    if (G < M) {
      int gsw = gg ^ (row & 7);
      u16x8 v = *reinterpret_cast<const u16x8*>(slab + row * 256 + gsw * 8);
      int col = gg * 8;
      if (col < 128)
        *reinterpret_cast<u16x8*>(proj + (size_t)G * 128 + col) = v;          // cached
      else
        __builtin_nontemporal_store(v,
            reinterpret_cast<u16x8*>(selfp + (size_t)G * 128 + (col - 128))); // streaming
    }
  }
}

// ==================== launch ====================
extern "C" void kernel_launch(void* const* d_in, const int* in_sizes, int n_in,
                              void* d_out, int out_size, void* d_ws, size_t ws_size,
                              hipStream_t stream) {
  const float* emb_user    = (const float*)d_in[0];
  const float* emb_item    = (const float*)d_in[1];
  const float* W1_self_ui  = (const float*)d_in[2];
  const float* W1_neigh_ui = (const float*)d_in[3];
  const float* b1_ui       = (const float*)d_in[4];
  const float* W1_self_iu  = (const float*)d_in[5];
  const float* W1_neigh_iu = (const float*)d_in[6];
  const float* b1_iu       = (const float*)d_in[7];
  const float* W2_self_ui  = (const float*)d_in[8];
  const float* W2_neigh_ui = (const float*)d_in[9];
  const float* b2_ui       = (const float*)d_in[10];
  const float* W2_self_iu  = (const float*)d_in[11];
  const float* W2_neigh_iu = (const float*)d_in[12];
  const float* b2_iu       = (const float*)d_in[13];
  const int* e1_src = (const int*)d_in[14];
  const int* e1_dst = (const int*)d_in[15];
  const int* e2_src = (const int*)d_in[16];
  const int* e2_dst = (const int*)d_in[17];

  // ---- workspace (no h1 buffers; proj/self dedicated — no aliasing with aggb) ----
  u16* p16 = (u16*)d_ws;
  u16* ue       = p16; p16 += (size_t)NUc * 128;
  u16* ie       = p16; p16 += (size_t)NIc * 128;
  u16* aggb_i   = p16; p16 += (size_t)NIc * 128;
  u16* aggb_u   = p16; p16 += (size_t)NUc * 128;
  u16* proj_u2i = p16; p16 += (size_t)NUc * 128;
  u16* self_u   = p16; p16 += (size_t)NUc * 128;
  u16* proj_i2u = p16; p16 += (size_t)NIc * 128;
  u16* self_i   = p16; p16 += (size_t)NIc * 128;
  u16* Wt1_ui   = p16; p16 += 256 * 256;
  u16* Wt1_iu   = p16; p16 += 256 * 256;
  u16* Wt2c_u   = p16; p16 += 256 * 256;
  u16* Wt2c_i   = p16; p16 += 256 * 256;
  int* ip    = (int*)p16;
  int* ideg1 = ip;  ip += NIc;
  int* ideg2 = ip;  ip += NUc;
  int* off1  = ip;  ip += NIc + 1;
  int* off2  = ip;  ip += NUc + 1;
  int* rank1 = ip;  ip += Ec;
  int* rank2 = ip;  ip += Ec;
  int* csr1  = ip;  ip += Ec;
  int* csr2  = ip;  ip += Ec;
  int* bsum1 = ip;  ip += 512;
  int* bscan1= ip;  ip += 512;
  int* bsum2 = ip;  ip += 512;
  int* bscan2= ip;  ip += 512;

  float* h2_user = (float*)d_out;
  float* h2_item = h2_user + (size_t)NUc * 128;

  dim3 blk(256);
  const int gatherBlocks = 2 * ((100000 + 63) / 64);   // 3126
  dim3 fusedGrid((100000 + 63) / 64, 1, 2);            // 1563 x 2

  // ---- CSR build + prep ----
  hipMemsetAsync(ideg1, 0, sizeof(int) * (size_t)(NIc + NUc), stream);
  hist_kernel<<<1024, blk, 0, stream>>>(e1_dst, e2_dst, ideg1, ideg2, rank1, rank2);
  prep_cast<<<PREP_B, blk, 0, stream>>>(
      emb_user, emb_item,
      W1_self_ui, W1_neigh_ui, W1_self_iu, W1_neigh_iu,
      W2_self_ui, W2_neigh_ui, W2_self_iu, W2_neigh_iu,
      ue, ie, Wt1_ui, Wt1_iu, Wt2c_u, Wt2c_i);
  block_reduce2<<<dim3(NB, 2), blk, 0, stream>>>(ideg1, ideg2, bsum1, bsum2, NIc);
  scan_bsums2<<<2, 512, 0, stream>>>(bsum1, bsum2, bscan1, bscan2, NB);
  scan_blocks2<<<dim3(NB, 2), blk, 0, stream>>>(ideg1, ideg2, bscan1, bscan2, off1, off2, NIc);
  fill_csr_kernel<<<1024, blk, 0, stream>>>(e1_src, e1_dst, e2_src, e2_dst,
                                            rank1, rank2, off1, off2, csr1, csr2);

  // ---- layer 1 gather ----
  gather_blk<0><<<gatherBlocks, blk, 0, stream>>>(
      ue, off1, csr1, nullptr, aggb_i,
      ie, off2, csr2, nullptr, aggb_u);

  // ---- fused L1+L2 GEMM (h1 stays on-chip) ----
  // z=0: h1i from (ie, aggb_i, Wt1_ui, b1_ui) -> Wt2c_i, b2_ui -> proj_i2u + self_i
  // z=1: h1u from (ue, aggb_u, Wt1_iu, b1_iu) -> Wt2c_u, b2_iu -> proj_u2i + self_u
  fused_gemm<<<fusedGrid, blk, 0, stream>>>(
      ie, aggb_i, Wt1_ui, b1_ui, Wt2c_i, b2_ui, proj_i2u, self_i,
      ue, aggb_u, Wt1_iu, b1_iu, Wt2c_u, b2_iu, proj_u2i, self_u, Mrows);

  // ---- layer 2 gather + final add -> f32 outputs ----
  gather_blk<1><<<gatherBlocks, blk, 0, stream>>>(
      proj_u2i, off1, csr1, self_i, h2_item,
      proj_i2u, off2, csr2, self_u, h2_user);
}

// Round 11
// 338.558 us; speedup vs baseline: 1.0264x; 1.0104x over previous
//
#include <hip/hip_runtime.h>
#include <stdint.h>

typedef unsigned short u16;
typedef unsigned int   u32;
typedef __attribute__((ext_vector_type(8))) short bf16x8;
typedef __attribute__((ext_vector_type(4))) float f32x4;
typedef __attribute__((ext_vector_type(2))) float f32x2;
typedef __attribute__((ext_vector_type(8))) unsigned short u16x8;

constexpr int NUc = 100000;
constexpr int NIc = 100000;
constexpr int Ec  = 500000;
constexpr int Mrows = 100000;
constexpr int NB  = (100000 + 255) / 256;   // 391 scan blocks

__device__ __forceinline__ u16 f2bf(float f) {
  u32 u = __float_as_uint(f);
  u += 0x7fffu + ((u >> 16) & 1u);          // round-to-nearest-even
  return (u16)(u >> 16);
}

// ==================== degree histogram + rank ====================
__global__ void hist_kernel(const int* __restrict__ e1_dst, const int* __restrict__ e2_dst,
                            int* __restrict__ ideg1, int* __restrict__ ideg2,
                            int* __restrict__ rank1, int* __restrict__ rank2) {
  int i = blockIdx.x * blockDim.x + threadIdx.x;
  const int stride = gridDim.x * blockDim.x;
  for (; i < 2 * Ec; i += stride) {
    if (i < Ec) rank1[i] = atomicAdd(&ideg1[e1_dst[i]], 1);
    else        rank2[i - Ec] = atomicAdd(&ideg2[e2_dst[i - Ec]], 1);
  }
}

// ==================== cast + weight prep ====================
constexpr int PREP_B = 4096;
__global__ void prep_cast(const float* __restrict__ eu, const float* __restrict__ ei,
                          const float* __restrict__ W1s_ui, const float* __restrict__ W1n_ui,
                          const float* __restrict__ W1s_iu, const float* __restrict__ W1n_iu,
                          const float* __restrict__ W2s_ui, const float* __restrict__ W2n_ui,
                          const float* __restrict__ W2s_iu, const float* __restrict__ W2n_iu,
                          u16* __restrict__ ue, u16* __restrict__ ie,
                          u16* __restrict__ Wt1_ui, u16* __restrict__ Wt1_iu,
                          u16* __restrict__ Wt2c_u, u16* __restrict__ Wt2c_i) {
  constexpr int N4 = NUc * 128 / 4;
  constexpr int TOT = 2 * N4 + 262144;
  int i = blockIdx.x * blockDim.x + threadIdx.x;
  const int stride = PREP_B * 256;
  for (int t = i; t < TOT; t += stride) {
    if (t < 2 * N4) {
      const float* src = (t < N4) ? eu : ei;
      u16* dst = (t < N4) ? ue : ie;
      int c = (t < N4) ? t : t - N4;
      f32x4 v = __builtin_nontemporal_load(reinterpret_cast<const f32x4*>(src) + c);
      ushort4 o;
      o.x = f2bf(v.x); o.y = f2bf(v.y); o.z = f2bf(v.z); o.w = f2bf(v.w);
      reinterpret_cast<ushort4*>(dst)[c] = o;   // cached: re-read by gather/gemm
    } else {
      int j = t - 2 * N4;
      if (j < 131072) {                      // Wt1 [256 outcol][256 k]
        const float* Ws = (j < 65536) ? W1s_ui : W1s_iu;
        const float* Wn = (j < 65536) ? W1n_ui : W1n_iu;
        u16* dst = (j < 65536) ? Wt1_ui : Wt1_iu;
        int q = j & 65535;
        int n = q >> 8, k = q & 255;
        dst[q] = f2bf(k < 128 ? Ws[k * 256 + n] : Wn[(k - 128) * 256 + n]);
      } else {                               // Wt2c [256 outcol][256 k]
        int q = j - 131072;
        int which = q >> 16;                 // 0: applied to h1u, 1: applied to h1i
        int s = q & 65535;
        int c = s >> 8, k = s & 255;
        float v;
        if (which == 0) v = (c < 128) ? W2n_ui[k * 128 + c] : W2s_iu[k * 128 + (c - 128)];
        else            v = (c < 128) ? W2n_iu[k * 128 + c] : W2s_ui[k * 128 + (c - 128)];
        u16* dst = which ? Wt2c_i : Wt2c_u;
        dst[s] = f2bf(v);
      }
    }
  }
}

// ==================== CSR scans ====================
__global__ void block_reduce2(const int* __restrict__ ideg1, const int* __restrict__ ideg2,
                              int* __restrict__ bsum1, int* __restrict__ bsum2, int n) {
  const int* deg = blockIdx.y ? ideg2 : ideg1;
  int* bsum = blockIdx.y ? bsum2 : bsum1;
  __shared__ int s[256];
  int t = threadIdx.x, i = blockIdx.x * 256 + t;
  s[t] = (i < n) ? deg[i] : 0;
  __syncthreads();
  for (int st = 128; st > 0; st >>= 1) { if (t < st) s[t] += s[t + st]; __syncthreads(); }
  if (t == 0) bsum[blockIdx.x] = s[0];
}

__global__ void scan_bsums2(const int* __restrict__ bsum1, const int* __restrict__ bsum2,
                            int* __restrict__ bscan1, int* __restrict__ bscan2, int nb) {
  const int* bsum = blockIdx.x ? bsum2 : bsum1;
  int* bscan = blockIdx.x ? bscan2 : bscan1;
  __shared__ int s[512];
  int t = threadIdx.x;
  int v0 = (t < nb) ? bsum[t] : 0;
  s[t] = v0;
  __syncthreads();
  for (int d = 1; d < 512; d <<= 1) {
    int v = (t >= d) ? s[t - d] : 0;
    __syncthreads();
    s[t] += v;
    __syncthreads();
  }
  if (t < nb) bscan[t] = s[t] - v0;   // exclusive
}

__global__ void scan_blocks2(const int* __restrict__ ideg1, const int* __restrict__ ideg2,
                             const int* __restrict__ bscan1, const int* __restrict__ bscan2,
                             int* __restrict__ off1, int* __restrict__ off2, int n) {
  const int* deg = blockIdx.y ? ideg2 : ideg1;
  const int* bscan = blockIdx.y ? bscan2 : bscan1;
  int* off = blockIdx.y ? off2 : off1;
  __shared__ int s[256];
  int t = threadIdx.x, i = blockIdx.x * 256 + t;
  int d = (i < n) ? deg[i] : 0;
  s[t] = d;
  __syncthreads();
  for (int st = 1; st < 256; st <<= 1) {
    int v = (t >= st) ? s[t - st] : 0;
    __syncthreads();
    s[t] += v;
    __syncthreads();
  }
  if (i < n) off[i] = bscan[blockIdx.x] + s[t] - d;
  if (i == 0) off[n] = Ec;
}

__global__ void fill_csr_kernel(const int* __restrict__ e1_src, const int* __restrict__ e1_dst,
                                const int* __restrict__ e2_src, const int* __restrict__ e2_dst,
                                const int* __restrict__ rank1, const int* __restrict__ rank2,
                                const int* __restrict__ off1, const int* __restrict__ off2,
                                int* __restrict__ csr1, int* __restrict__ csr2) {
  int i = blockIdx.x * blockDim.x + threadIdx.x;
  const int stride = gridDim.x * blockDim.x;
  for (; i < 2 * Ec; i += stride) {
    if (i < Ec) {
      int d = __builtin_nontemporal_load(e1_dst + i);
      int r = __builtin_nontemporal_load(rank1 + i);
      csr1[off1[d] + r] = __builtin_nontemporal_load(e1_src + i);
    } else {
      int e = i - Ec;
      int d = __builtin_nontemporal_load(e2_dst + e);
      int r = __builtin_nontemporal_load(rank2 + e);
      csr2[off2[d] + r] = __builtin_nontemporal_load(e2_src + e);
    }
  }
}

// ==================== block-staged CSR gather (unchanged) ====================
template<int FINAL>
__global__ __launch_bounds__(256) void gather_blk(
    const u16* __restrict__ fA, const int* __restrict__ offA, const int* __restrict__ csrA,
    const u16* __restrict__ sA, void* __restrict__ outA,
    const u16* __restrict__ fB, const int* __restrict__ offB, const int* __restrict__ csrB,
    const u16* __restrict__ sB, void* __restrict__ outB)
{
  constexpr int ROWS = 64;
  constexpr int CAP  = 1536;
  constexpr int NBLK = (100000 + ROWS - 1) / ROWS;   // 1563
  __shared__ int s_off[ROWS + 1];
  __shared__ int s_csr[CAP];

  const int b = blockIdx.x;
  const u16* f; const int* off; const int* csr; const u16* sf; void* out; int r0;
  if (b < NBLK) { f = fA; off = offA; csr = csrA; sf = sA; out = outA; r0 = b * ROWS; }
  else          { f = fB; off = offB; csr = csrB; sf = sB; out = outB; r0 = (b - NBLK) * ROWS; }

  const int tid = threadIdx.x;
  if (tid <= ROWS) s_off[tid] = off[min(r0 + tid, 100000)];
  __syncthreads();
  const int j0 = s_off[0];
  const int nE = s_off[ROWS] - j0;
  const bool inLds = (nE <= CAP);
  if (inLds) {
    for (int j = tid; j < nE; j += 256) s_csr[j] = csr[j0 + j];
  }
  __syncthreads();

  const int w = tid >> 6, lane = tid & 63;
  const int colb = lane << 1;
  for (int rr = w; rr < ROWS; rr += 4) {
    const int r = r0 + rr;
    if (r >= 100000) break;
    const int a0 = s_off[rr], a1 = s_off[rr + 1];
    float ax = 0.f, ay = 0.f;
    if (inLds) {
      int tl = a0 - j0;
      const int el = a1 - j0;
      for (; tl + 4 <= el; tl += 4) {
        int s0 = s_csr[tl], s1 = s_csr[tl + 1], s2 = s_csr[tl + 2], s3 = s_csr[tl + 3];
        u32 v0 = *reinterpret_cast<const u32*>(f + (size_t)s0 * 128 + colb);
        u32 v1 = *reinterpret_cast<const u32*>(f + (size_t)s1 * 128 + colb);
        u32 v2 = *reinterpret_cast<const u32*>(f + (size_t)s2 * 128 + colb);
        u32 v3 = *reinterpret_cast<const u32*>(f + (size_t)s3 * 128 + colb);
        ax += __uint_as_float(v0 << 16) + __uint_as_float(v1 << 16)
            + __uint_as_float(v2 << 16) + __uint_as_float(v3 << 16);
        ay += __uint_as_float(v0 & 0xffff0000u) + __uint_as_float(v1 & 0xffff0000u)
            + __uint_as_float(v2 & 0xffff0000u) + __uint_as_float(v3 & 0xffff0000u);
      }
      for (; tl < el; ++tl) {
        int s0 = s_csr[tl];
        u32 v0 = *reinterpret_cast<const u32*>(f + (size_t)s0 * 128 + colb);
        ax += __uint_as_float(v0 << 16);
        ay += __uint_as_float(v0 & 0xffff0000u);
      }
    } else {
      int t = a0;
      for (; t + 4 <= a1; t += 4) {
        int s0 = csr[t], s1 = csr[t + 1], s2 = csr[t + 2], s3 = csr[t + 3];
        u32 v0 = *reinterpret_cast<const u32*>(f + (size_t)s0 * 128 + colb);
        u32 v1 = *reinterpret_cast<const u32*>(f + (size_t)s1 * 128 + colb);
        u32 v2 = *reinterpret_cast<const u32*>(f + (size_t)s2 * 128 + colb);
        u32 v3 = *reinterpret_cast<const u32*>(f + (size_t)s3 * 128 + colb);
        ax += __uint_as_float(v0 << 16) + __uint_as_float(v1 << 16)
            + __uint_as_float(v2 << 16) + __uint_as_float(v3 << 16);
        ay += __uint_as_float(v0 & 0xffff0000u) + __uint_as_float(v1 & 0xffff0000u)
            + __uint_as_float(v2 & 0xffff0000u) + __uint_as_float(v3 & 0xffff0000u);
      }
      for (; t < a1; ++t) {
        int s0 = csr[t];
        u32 v0 = *reinterpret_cast<const u32*>(f + (size_t)s0 * 128 + colb);
        ax += __uint_as_float(v0 << 16);
        ay += __uint_as_float(v0 & 0xffff0000u);
      }
    }
    float rs = 1.0f / fmaxf((float)(a1 - a0), 1.0f);
    if (FINAL) {
      u32 sv = __builtin_nontemporal_load(
          reinterpret_cast<const u32*>(sf + (size_t)r * 128 + colb));
      f32x2 o;
      o.x = ax * rs + __uint_as_float(sv << 16);
      o.y = ay * rs + __uint_as_float(sv & 0xffff0000u);
      __builtin_nontemporal_store(o, reinterpret_cast<f32x2*>((float*)out + (size_t)r * 128 + colb));
    } else {
      u32 o = (u32)f2bf(ax * rs) | ((u32)f2bf(ay * rs) << 16);
      *reinterpret_cast<u32*>((u16*)out + (size_t)r * 128 + colb) = o;
    }
  }
}

// ==================== FUSED layer1+layer2 GEMM, software-pipelined ====================
// Double-buffered As/Bs; next K-step staged BEFORE computing current; ONE barrier per
// K-step (its vmcnt drain lands after staging had the whole MFMA phase in flight).
// Phase transitions prefetch: last phase-1 iter stages W2's first tile.
__device__ __forceinline__ void glds16(const void* g, void* l) {
  __builtin_amdgcn_global_load_lds((const __attribute__((address_space(1))) void*)g,
                                   (__attribute__((address_space(3))) void*)l, 16, 0, 0);
}

__global__ __launch_bounds__(256) void fused_gemm(
    const u16* __restrict__ Xa, const u16* __restrict__ Sa,
    const u16* __restrict__ W1a, const float* __restrict__ b1a,
    const u16* __restrict__ W2a, const float* __restrict__ b2a,
    u16* __restrict__ proja, u16* __restrict__ selfa,
    const u16* __restrict__ Xb, const u16* __restrict__ Sb,
    const u16* __restrict__ W1b, const float* __restrict__ b1b,
    const u16* __restrict__ W2b, const float* __restrict__ b2b,
    u16* __restrict__ projb, u16* __restrict__ selfb,
    int M)
{
  constexpr int K = 256, BK = 32, BM = 64;
  __shared__ __align__(16) u16 As0[BM * BK];      // 4 KB
  __shared__ __align__(16) u16 Bs0[256 * BK];     // 16 KB
  __shared__ __align__(16) u16 As1[BM * BK];      // 4 KB
  __shared__ __align__(16) u16 Bs1[256 * BK];     // 16 KB
  __shared__ __align__(16) u16 slab[BM * 256];    // 32 KB   (total 72 KB)

  const bool zb = (blockIdx.z != 0);
  const u16* X   = zb ? Xb : Xa;
  const u16* S   = zb ? Sb : Sa;
  const u16* W1  = zb ? W1b : W1a;
  const float* b1 = zb ? b1b : b1a;
  const u16* W2  = zb ? W2b : W2a;
  const float* b2 = zb ? b2b : b2a;
  u16* proj  = zb ? projb : proja;
  u16* selfp = zb ? selfb : selfa;

  const int tid  = threadIdx.x;
  const int lane = tid & 63;
  const int w    = tid >> 6;           // wave 0..3 -> col-tile w*64
  const int gr0  = blockIdx.x * BM;
  const int rl   = tid >> 2;           // stage row 0..63
  const int sslot = tid & 3;           // stage 16B slot

  // wave-uniform staging bases + precomputed per-thread global pieces
  const int aswz = (sslot ^ ((rl >> 1) & 3)) << 3;
  int grow = gr0 + rl; grow = grow < M ? grow : M - 1;
  const size_t arow = (size_t)grow * 128 + aswz;

  auto stageA1 = [&](int kt, u16* Asb) {
    const u16* At = (kt >= 128) ? S : X;
    glds16(At + arow + (kt & 127), Asb + (size_t)(w * 16) * BK);
  };
  auto stageB = [&](const u16* W, int kt, u16* Bsb) {
    #pragma unroll
    for (int h = 0; h < 4; ++h) {
      int rb = h * 64 + rl;
      int swz = (sslot ^ ((rb >> 1) & 3)) << 3;
      glds16(W + (size_t)rb * K + kt + swz, Bsb + (size_t)(h * 64 + w * 16) * BK);
    }
  };

  f32x4 acc[4][4];
  #pragma unroll
  for (int m = 0; m < 4; ++m)
    #pragma unroll
    for (int n = 0; n < 4; ++n) acc[m][n] = (f32x4){0.f, 0.f, 0.f, 0.f};

  // ---- prologue: stage k=0 into buf0 ----
  stageA1(0, As0);
  stageB(W1, 0, Bs0);
  __syncthreads();

  // ---- phase 1: h1 = [X;S] @ W1 (pipelined) ----
  int db = 0;
  for (int kt = 0; kt < K; kt += BK) {
    u16* AsN = db ? As0 : As1;
    u16* BsN = db ? Bs0 : Bs1;
    if (kt + BK < K) {
      stageA1(kt + BK, AsN);
      stageB(W1, kt + BK, BsN);
    } else {
      stageB(W2, 0, BsN);                 // prefetch phase-3 first tile
    }
    const u16* Asb = db ? As1 : As0;
    const u16* Bsb = db ? Bs1 : Bs0;

    bf16x8 af[4], bfr[4];
    #pragma unroll
    for (int m = 0; m < 4; ++m) {
      int row = m * 16 + (lane & 15);
      int idx = (row << 5) + ((((lane >> 4) ^ ((row >> 1) & 3))) << 3);
      af[m] = *reinterpret_cast<const bf16x8*>(Asb + idx);
    }
    #pragma unroll
    for (int n = 0; n < 4; ++n) {
      int row = w * 64 + n * 16 + (lane & 15);
      int idx = (row << 5) + ((((lane >> 4) ^ ((row >> 1) & 3))) << 3);
      bfr[n] = *reinterpret_cast<const bf16x8*>(Bsb + idx);
    }
    #pragma unroll
    for (int m = 0; m < 4; ++m)
      #pragma unroll
      for (int n = 0; n < 4; ++n)
        acc[m][n] = __builtin_amdgcn_mfma_f32_16x16x32_bf16(af[m], bfr[n], acc[m][n], 0, 0, 0);
    __syncthreads();
    db ^= 1;
  }

  // ---- phase 2: leaky(h1 + b1) -> slab (granule-swizzled bf16) ----
  #pragma unroll
  for (int n = 0; n < 4; ++n) {
    int c = w * 64 + n * 16 + (lane & 15);
    float b = b1[c];
    #pragma unroll
    for (int m = 0; m < 4; ++m) {
      #pragma unroll
      for (int r = 0; r < 4; ++r) {
        int row = m * 16 + ((lane >> 4) << 2) + r;
        float v = acc[m][n][r] + b;
        v = (v >= 0.f) ? v : 0.01f * v;
        int g = (c >> 3) ^ (row & 7);
        slab[row * 256 + g * 8 + (c & 7)] = f2bf(v);
        acc[m][n][r] = 0.f;
      }
    }
  }
  __syncthreads();   // drains the W2 k=0 prefetch too

  // ---- phase 3: [proj|self] = slab @ W2c (pipelined) ----
  for (int kt = 0; kt < K; kt += BK) {
    u16* BsN = db ? Bs0 : Bs1;
    if (kt + BK < K) stageB(W2, kt + BK, BsN);
    const u16* Bsb = db ? Bs1 : Bs0;

    bf16x8 af[4], bfr[4];
    #pragma unroll
    for (int m = 0; m < 4; ++m) {
      int row = m * 16 + (lane & 15);
      int g = ((kt >> 3) + (lane >> 4)) ^ (row & 7);
      af[m] = *reinterpret_cast<const bf16x8*>(slab + row * 256 + g * 8);
    }
    #pragma unroll
    for (int n = 0; n < 4; ++n) {
      int row = w * 64 + n * 16 + (lane & 15);
      int idx = (row << 5) + ((((lane >> 4) ^ ((row >> 1) & 3))) << 3);
      bfr[n] = *reinterpret_cast<const bf16x8*>(Bsb + idx);
    }
    #pragma unroll
    for (int m = 0; m < 4; ++m)
      #pragma unroll
      for (int n = 0; n < 4; ++n)
        acc[m][n] = __builtin_amdgcn_mfma_f32_16x16x32_bf16(af[m], bfr[n], acc[m][n], 0, 0, 0);
    __syncthreads();
    db ^= 1;
  }

  // ---- phase 4: epilogue via slab ----
  #pragma unroll
  for (int n = 0; n < 4; ++n) {
    int c = w * 64 + n * 16 + (lane & 15);
    float b = (c >= 128) ? b2[c - 128] : 0.f;
    #pragma unroll
    for (int m = 0; m < 4; ++m) {
      #pragma unroll
      for (int r = 0; r < 4; ++r) {
        int row = m * 16 + ((lane >> 4) << 2) + r;
        int g = (c >> 3) ^ (row & 7);
        slab[row * 256 + g * 8 + (c & 7)] = f2bf(acc[m][n][r] + b);
      }
    }
  }
  __syncthreads();
  #pragma unroll
  for (int p = 0; p < 8; ++p) {
    int chunk = p * 256 + tid;
    int row = chunk >> 5;            // 0..63
    int gg  = chunk & 31;            // output granule (8 cols)
    int G = gr0 + row;
    if (G < M) {
      int gsw = gg ^ (row & 7);
      u16x8 v = *reinterpret_cast<const u16x8*>(slab + row * 256 + gsw * 8);
      int col = gg * 8;
      if (col < 128)
        *reinterpret_cast<u16x8*>(proj + (size_t)G * 128 + col) = v;          // cached
      else
        __builtin_nontemporal_store(v,
            reinterpret_cast<u16x8*>(selfp + (size_t)G * 128 + (col - 128))); // streaming
    }
  }
}

// ==================== launch ====================
extern "C" void kernel_launch(void* const* d_in, const int* in_sizes, int n_in,
                              void* d_out, int out_size, void* d_ws, size_t ws_size,
                              hipStream_t stream) {
  const float* emb_user    = (const float*)d_in[0];
  const float* emb_item    = (const float*)d_in[1];
  const float* W1_self_ui  = (const float*)d_in[2];
  const float* W1_neigh_ui = (const float*)d_in[3];
  const float* b1_ui       = (const float*)d_in[4];
  const float* W1_self_iu  = (const float*)d_in[5];
  const float* W1_neigh_iu = (const float*)d_in[6];
  const float* b1_iu       = (const float*)d_in[7];
  const float* W2_self_ui  = (const float*)d_in[8];
  const float* W2_neigh_ui = (const float*)d_in[9];
  const float* b2_ui       = (const float*)d_in[10];
  const float* W2_self_iu  = (const float*)d_in[11];
  const float* W2_neigh_iu = (const float*)d_in[12];
  const float* b2_iu       = (const float*)d_in[13];
  const int* e1_src = (const int*)d_in[14];
  const int* e1_dst = (const int*)d_in[15];
  const int* e2_src = (const int*)d_in[16];
  const int* e2_dst = (const int*)d_in[17];

  // ---- workspace ----
  u16* p16 = (u16*)d_ws;
  u16* ue       = p16; p16 += (size_t)NUc * 128;
  u16* ie       = p16; p16 += (size_t)NIc * 128;
  u16* aggb_i   = p16; p16 += (size_t)NIc * 128;
  u16* aggb_u   = p16; p16 += (size_t)NUc * 128;
  u16* proj_u2i = p16; p16 += (size_t)NUc * 128;
  u16* self_u   = p16; p16 += (size_t)NUc * 128;
  u16* proj_i2u = p16; p16 += (size_t)NIc * 128;
  u16* self_i   = p16; p16 += (size_t)NIc * 128;
  u16* Wt1_ui   = p16; p16 += 256 * 256;
  u16* Wt1_iu   = p16; p16 += 256 * 256;
  u16* Wt2c_u   = p16; p16 += 256 * 256;
  u16* Wt2c_i   = p16; p16 += 256 * 256;
  int* ip    = (int*)p16;
  int* ideg1 = ip;  ip += NIc;
  int* ideg2 = ip;  ip += NUc;
  int* off1  = ip;  ip += NIc + 1;
  int* off2  = ip;  ip += NUc + 1;
  int* rank1 = ip;  ip += Ec;
  int* rank2 = ip;  ip += Ec;
  int* csr1  = ip;  ip += Ec;
  int* csr2  = ip;  ip += Ec;
  int* bsum1 = ip;  ip += 512;
  int* bscan1= ip;  ip += 512;
  int* bsum2 = ip;  ip += 512;
  int* bscan2= ip;  ip += 512;

  float* h2_user = (float*)d_out;
  float* h2_item = h2_user + (size_t)NUc * 128;

  dim3 blk(256);
  const int gatherBlocks = 2 * ((100000 + 63) / 64);   // 3126
  dim3 fusedGrid((100000 + 63) / 64, 1, 2);            // 1563 x 2

  // ---- CSR build + prep ----
  hipMemsetAsync(ideg1, 0, sizeof(int) * (size_t)(NIc + NUc), stream);
  hist_kernel<<<1024, blk, 0, stream>>>(e1_dst, e2_dst, ideg1, ideg2, rank1, rank2);
  prep_cast<<<PREP_B, blk, 0, stream>>>(
      emb_user, emb_item,
      W1_self_ui, W1_neigh_ui, W1_self_iu, W1_neigh_iu,
      W2_self_ui, W2_neigh_ui, W2_self_iu, W2_neigh_iu,
      ue, ie, Wt1_ui, Wt1_iu, Wt2c_u, Wt2c_i);
  block_reduce2<<<dim3(NB, 2), blk, 0, stream>>>(ideg1, ideg2, bsum1, bsum2, NIc);
  scan_bsums2<<<2, 512, 0, stream>>>(bsum1, bsum2, bscan1, bscan2, NB);
  scan_blocks2<<<dim3(NB, 2), blk, 0, stream>>>(ideg1, ideg2, bscan1, bscan2, off1, off2, NIc);
  fill_csr_kernel<<<1024, blk, 0, stream>>>(e1_src, e1_dst, e2_src, e2_dst,
                                            rank1, rank2, off1, off2, csr1, csr2);

  // ---- layer 1 gather ----
  gather_blk<0><<<gatherBlocks, blk, 0, stream>>>(
      ue, off1, csr1, nullptr, aggb_i,
      ie, off2, csr2, nullptr, aggb_u);

  // ---- fused L1+L2 GEMM (h1 stays on-chip) ----
  fused_gemm<<<fusedGrid, blk, 0, stream>>>(
      ie, aggb_i, Wt1_ui, b1_ui, Wt2c_i, b2_ui, proj_i2u, self_i,
      ue, aggb_u, Wt1_iu, b1_iu, Wt2c_u, b2_iu, proj_u2i, self_u, Mrows);

  // ---- layer 2 gather + final add -> f32 outputs ----
  gather_blk<1><<<gatherBlocks, blk, 0, stream>>>(
      proj_u2i, off1, csr1, self_i, h2_item,
      proj_i2u, off2, csr2, self_u, h2_user);
}

// Round 12
// 333.336 us; speedup vs baseline: 1.0425x; 1.0157x over previous
//
#include <hip/hip_runtime.h>
#include <stdint.h>

typedef unsigned short u16;
typedef unsigned int   u32;
typedef __attribute__((ext_vector_type(8))) short bf16x8;
typedef __attribute__((ext_vector_type(4))) float f32x4;
typedef __attribute__((ext_vector_type(2))) float f32x2;
typedef __attribute__((ext_vector_type(8))) unsigned short u16x8;

constexpr int NUc = 100000;
constexpr int NIc = 100000;
constexpr int Ec  = 500000;
constexpr int Mrows = 100000;
constexpr int NB  = (100000 + 255) / 256;   // 391 scan blocks

__device__ __forceinline__ u16 f2bf(float f) {
  u32 u = __float_as_uint(f);
  u += 0x7fffu + ((u >> 16) & 1u);          // round-to-nearest-even
  return (u16)(u >> 16);
}

// ==================== degree histogram + rank ====================
__global__ void hist_kernel(const int* __restrict__ e1_dst, const int* __restrict__ e2_dst,
                            int* __restrict__ ideg1, int* __restrict__ ideg2,
                            int* __restrict__ rank1, int* __restrict__ rank2) {
  int i = blockIdx.x * blockDim.x + threadIdx.x;
  const int stride = gridDim.x * blockDim.x;
  for (; i < 2 * Ec; i += stride) {
    if (i < Ec) rank1[i] = atomicAdd(&ideg1[e1_dst[i]], 1);
    else        rank2[i - Ec] = atomicAdd(&ideg2[e2_dst[i - Ec]], 1);
  }
}

// ==================== cast + weight prep ====================
constexpr int PREP_B = 4096;
__global__ void prep_cast(const float* __restrict__ eu, const float* __restrict__ ei,
                          const float* __restrict__ W1s_ui, const float* __restrict__ W1n_ui,
                          const float* __restrict__ W1s_iu, const float* __restrict__ W1n_iu,
                          const float* __restrict__ W2s_ui, const float* __restrict__ W2n_ui,
                          const float* __restrict__ W2s_iu, const float* __restrict__ W2n_iu,
                          u16* __restrict__ ue, u16* __restrict__ ie,
                          u16* __restrict__ Wt1_ui, u16* __restrict__ Wt1_iu,
                          u16* __restrict__ Wt2c_u, u16* __restrict__ Wt2c_i) {
  constexpr int N4 = NUc * 128 / 4;
  constexpr int TOT = 2 * N4 + 262144;
  int i = blockIdx.x * blockDim.x + threadIdx.x;
  const int stride = PREP_B * 256;
  for (int t = i; t < TOT; t += stride) {
    if (t < 2 * N4) {
      const float* src = (t < N4) ? eu : ei;
      u16* dst = (t < N4) ? ue : ie;
      int c = (t < N4) ? t : t - N4;
      f32x4 v = __builtin_nontemporal_load(reinterpret_cast<const f32x4*>(src) + c);
      ushort4 o;
      o.x = f2bf(v.x); o.y = f2bf(v.y); o.z = f2bf(v.z); o.w = f2bf(v.w);
      reinterpret_cast<ushort4*>(dst)[c] = o;   // cached: re-read by gather/gemm
    } else {
      int j = t - 2 * N4;
      if (j < 131072) {                      // Wt1 [256 outcol][256 k]
        const float* Ws = (j < 65536) ? W1s_ui : W1s_iu;
        const float* Wn = (j < 65536) ? W1n_ui : W1n_iu;
        u16* dst = (j < 65536) ? Wt1_ui : Wt1_iu;
        int q = j & 65535;
        int n = q >> 8, k = q & 255;
        dst[q] = f2bf(k < 128 ? Ws[k * 256 + n] : Wn[(k - 128) * 256 + n]);
      } else {                               // Wt2c [256 outcol][256 k]
        int q = j - 131072;
        int which = q >> 16;                 // 0: applied to h1u, 1: applied to h1i
        int s = q & 65535;
        int c = s >> 8, k = s & 255;
        float v;
        if (which == 0) v = (c < 128) ? W2n_ui[k * 128 + c] : W2s_iu[k * 128 + (c - 128)];
        else            v = (c < 128) ? W2n_iu[k * 128 + c] : W2s_ui[k * 128 + (c - 128)];
        u16* dst = which ? Wt2c_i : Wt2c_u;
        dst[s] = f2bf(v);
      }
    }
  }
}

// ==================== CSR scans ====================
__global__ void block_reduce2(const int* __restrict__ ideg1, const int* __restrict__ ideg2,
                              int* __restrict__ bsum1, int* __restrict__ bsum2, int n) {
  const int* deg = blockIdx.y ? ideg2 : ideg1;
  int* bsum = blockIdx.y ? bsum2 : bsum1;
  __shared__ int s[256];
  int t = threadIdx.x, i = blockIdx.x * 256 + t;
  s[t] = (i < n) ? deg[i] : 0;
  __syncthreads();
  for (int st = 128; st > 0; st >>= 1) { if (t < st) s[t] += s[t + st]; __syncthreads(); }
  if (t == 0) bsum[blockIdx.x] = s[0];
}

__global__ void scan_bsums2(const int* __restrict__ bsum1, const int* __restrict__ bsum2,
                            int* __restrict__ bscan1, int* __restrict__ bscan2, int nb) {
  const int* bsum = blockIdx.x ? bsum2 : bsum1;
  int* bscan = blockIdx.x ? bscan2 : bscan1;
  __shared__ int s[512];
  int t = threadIdx.x;
  int v0 = (t < nb) ? bsum[t] : 0;
  s[t] = v0;
  __syncthreads();
  for (int d = 1; d < 512; d <<= 1) {
    int v = (t >= d) ? s[t - d] : 0;
    __syncthreads();
    s[t] += v;
    __syncthreads();
  }
  if (t < nb) bscan[t] = s[t] - v0;   // exclusive
}

__global__ void scan_blocks2(const int* __restrict__ ideg1, const int* __restrict__ ideg2,
                             const int* __restrict__ bscan1, const int* __restrict__ bscan2,
                             int* __restrict__ off1, int* __restrict__ off2, int n) {
  const int* deg = blockIdx.y ? ideg2 : ideg1;
  const int* bscan = blockIdx.y ? bscan2 : bscan1;
  int* off = blockIdx.y ? off2 : off1;
  __shared__ int s[256];
  int t = threadIdx.x, i = blockIdx.x * 256 + t;
  int d = (i < n) ? deg[i] : 0;
  s[t] = d;
  __syncthreads();
  for (int st = 1; st < 256; st <<= 1) {
    int v = (t >= st) ? s[t - st] : 0;
    __syncthreads();
    s[t] += v;
    __syncthreads();
  }
  if (i < n) off[i] = bscan[blockIdx.x] + s[t] - d;
  if (i == 0) off[n] = Ec;
}

__global__ void fill_csr_kernel(const int* __restrict__ e1_src, const int* __restrict__ e1_dst,
                                const int* __restrict__ e2_src, const int* __restrict__ e2_dst,
                                const int* __restrict__ rank1, const int* __restrict__ rank2,
                                const int* __restrict__ off1, const int* __restrict__ off2,
                                int* __restrict__ csr1, int* __restrict__ csr2) {
  int i = blockIdx.x * blockDim.x + threadIdx.x;
  const int stride = gridDim.x * blockDim.x;
  for (; i < 2 * Ec; i += stride) {
    if (i < Ec) {
      int d = __builtin_nontemporal_load(e1_dst + i);
      int r = __builtin_nontemporal_load(rank1 + i);
      csr1[off1[d] + r] = __builtin_nontemporal_load(e1_src + i);
    } else {
      int e = i - Ec;
      int d = __builtin_nontemporal_load(e2_dst + e);
      int r = __builtin_nontemporal_load(rank2 + e);
      csr2[off2[d] + r] = __builtin_nontemporal_load(e2_src + e);
    }
  }
}

// ==================== block-staged CSR gather (unchanged) ====================
template<int FINAL>
__global__ __launch_bounds__(256) void gather_blk(
    const u16* __restrict__ fA, const int* __restrict__ offA, const int* __restrict__ csrA,
    const u16* __restrict__ sA, void* __restrict__ outA,
    const u16* __restrict__ fB, const int* __restrict__ offB, const int* __restrict__ csrB,
    const u16* __restrict__ sB, void* __restrict__ outB)
{
  constexpr int ROWS = 64;
  constexpr int CAP  = 1536;
  constexpr int NBLK = (100000 + ROWS - 1) / ROWS;   // 1563
  __shared__ int s_off[ROWS + 1];
  __shared__ int s_csr[CAP];

  const int b = blockIdx.x;
  const u16* f; const int* off; const int* csr; const u16* sf; void* out; int r0;
  if (b < NBLK) { f = fA; off = offA; csr = csrA; sf = sA; out = outA; r0 = b * ROWS; }
  else          { f = fB; off = offB; csr = csrB; sf = sB; out = outB; r0 = (b - NBLK) * ROWS; }

  const int tid = threadIdx.x;
  if (tid <= ROWS) s_off[tid] = off[min(r0 + tid, 100000)];
  __syncthreads();
  const int j0 = s_off[0];
  const int nE = s_off[ROWS] - j0;
  const bool inLds = (nE <= CAP);
  if (inLds) {
    for (int j = tid; j < nE; j += 256) s_csr[j] = csr[j0 + j];
  }
  __syncthreads();

  const int w = tid >> 6, lane = tid & 63;
  const int colb = lane << 1;
  for (int rr = w; rr < ROWS; rr += 4) {
    const int r = r0 + rr;
    if (r >= 100000) break;
    const int a0 = s_off[rr], a1 = s_off[rr + 1];
    float ax = 0.f, ay = 0.f;
    if (inLds) {
      int tl = a0 - j0;
      const int el = a1 - j0;
      for (; tl + 4 <= el; tl += 4) {
        int s0 = s_csr[tl], s1 = s_csr[tl + 1], s2 = s_csr[tl + 2], s3 = s_csr[tl + 3];
        u32 v0 = *reinterpret_cast<const u32*>(f + (size_t)s0 * 128 + colb);
        u32 v1 = *reinterpret_cast<const u32*>(f + (size_t)s1 * 128 + colb);
        u32 v2 = *reinterpret_cast<const u32*>(f + (size_t)s2 * 128 + colb);
        u32 v3 = *reinterpret_cast<const u32*>(f + (size_t)s3 * 128 + colb);
        ax += __uint_as_float(v0 << 16) + __uint_as_float(v1 << 16)
            + __uint_as_float(v2 << 16) + __uint_as_float(v3 << 16);
        ay += __uint_as_float(v0 & 0xffff0000u) + __uint_as_float(v1 & 0xffff0000u)
            + __uint_as_float(v2 & 0xffff0000u) + __uint_as_float(v3 & 0xffff0000u);
      }
      for (; tl < el; ++tl) {
        int s0 = s_csr[tl];
        u32 v0 = *reinterpret_cast<const u32*>(f + (size_t)s0 * 128 + colb);
        ax += __uint_as_float(v0 << 16);
        ay += __uint_as_float(v0 & 0xffff0000u);
      }
    } else {
      int t = a0;
      for (; t + 4 <= a1; t += 4) {
        int s0 = csr[t], s1 = csr[t + 1], s2 = csr[t + 2], s3 = csr[t + 3];
        u32 v0 = *reinterpret_cast<const u32*>(f + (size_t)s0 * 128 + colb);
        u32 v1 = *reinterpret_cast<const u32*>(f + (size_t)s1 * 128 + colb);
        u32 v2 = *reinterpret_cast<const u32*>(f + (size_t)s2 * 128 + colb);
        u32 v3 = *reinterpret_cast<const u32*>(f + (size_t)s3 * 128 + colb);
        ax += __uint_as_float(v0 << 16) + __uint_as_float(v1 << 16)
            + __uint_as_float(v2 << 16) + __uint_as_float(v3 << 16);
        ay += __uint_as_float(v0 & 0xffff0000u) + __uint_as_float(v1 & 0xffff0000u)
            + __uint_as_float(v2 & 0xffff0000u) + __uint_as_float(v3 & 0xffff0000u);
      }
      for (; t < a1; ++t) {
        int s0 = csr[t];
        u32 v0 = *reinterpret_cast<const u32*>(f + (size_t)s0 * 128 + colb);
        ax += __uint_as_float(v0 << 16);
        ay += __uint_as_float(v0 & 0xffff0000u);
      }
    }
    float rs = 1.0f / fmaxf((float)(a1 - a0), 1.0f);
    if (FINAL) {
      u32 sv = __builtin_nontemporal_load(
          reinterpret_cast<const u32*>(sf + (size_t)r * 128 + colb));
      f32x2 o;
      o.x = ax * rs + __uint_as_float(sv << 16);
      o.y = ay * rs + __uint_as_float(sv & 0xffff0000u);
      __builtin_nontemporal_store(o, reinterpret_cast<f32x2*>((float*)out + (size_t)r * 128 + colb));
    } else {
      u32 o = (u32)f2bf(ax * rs) | ((u32)f2bf(ay * rs) << 16);
      *reinterpret_cast<u32*>((u16*)out + (size_t)r * 128 + colb) = o;
    }
  }
}

// ==================== FUSED layer1+layer2 GEMM, counted-vmcnt pipeline (T4) ====================
// Per K-step: [stage t+1][s_waitcnt vmcnt(5)][s_barrier][compute t][s_barrier raw].
// The counted wait drains ONLY tile t; tile t+1's loads stay in flight across the MFMA.
// __syncthreads is avoided in the K-loops (its implicit vmcnt(0) drain kills the pipeline).
__device__ __forceinline__ void glds16(const void* g, void* l) {
  __builtin_amdgcn_global_load_lds((const __attribute__((address_space(1))) void*)g,
                                   (__attribute__((address_space(3))) void*)l, 16, 0, 0);
}

__global__ __launch_bounds__(256) void fused_gemm(
    const u16* __restrict__ Xa, const u16* __restrict__ Sa,
    const u16* __restrict__ W1a, const float* __restrict__ b1a,
    const u16* __restrict__ W2a, const float* __restrict__ b2a,
    u16* __restrict__ proja, u16* __restrict__ selfa,
    const u16* __restrict__ Xb, const u16* __restrict__ Sb,
    const u16* __restrict__ W1b, const float* __restrict__ b1b,
    const u16* __restrict__ W2b, const float* __restrict__ b2b,
    u16* __restrict__ projb, u16* __restrict__ selfb,
    int M)
{
  constexpr int K = 256, BK = 32, BM = 64;
  __shared__ __align__(16) u16 As0[BM * BK];      // 4 KB
  __shared__ __align__(16) u16 Bs0[256 * BK];     // 16 KB
  __shared__ __align__(16) u16 As1[BM * BK];      // 4 KB
  __shared__ __align__(16) u16 Bs1[256 * BK];     // 16 KB
  __shared__ __align__(16) u16 slab[BM * 256];    // 32 KB   (total 72 KB)

  const bool zb = (blockIdx.z != 0);
  const u16* X   = zb ? Xb : Xa;
  const u16* S   = zb ? Sb : Sa;
  const u16* W1  = zb ? W1b : W1a;
  const float* b1 = zb ? b1b : b1a;
  const u16* W2  = zb ? W2b : W2a;
  const float* b2 = zb ? b2b : b2a;
  u16* proj  = zb ? projb : proja;
  u16* selfp = zb ? selfb : selfa;

  const int tid  = threadIdx.x;
  const int lane = tid & 63;
  const int w    = tid >> 6;           // wave 0..3 -> col-tile w*64
  const int gr0  = blockIdx.x * BM;
  const int rl   = tid >> 2;           // stage row 0..63
  const int sslot = tid & 3;           // stage 16B slot

  const int aswz = (sslot ^ ((rl >> 1) & 3)) << 3;
  int grow = gr0 + rl; grow = grow < M ? grow : M - 1;
  const size_t arow = (size_t)grow * 128 + aswz;

  auto stageA1 = [&](int kt, u16* Asb) {
    const u16* At = (kt >= 128) ? S : X;
    glds16(At + arow + (kt & 127), Asb + (size_t)(w * 16) * BK);
  };
  auto stageB = [&](const u16* W, int kt, u16* Bsb) {
    #pragma unroll
    for (int h = 0; h < 4; ++h) {
      int rb = h * 64 + rl;
      int swz = (sslot ^ ((rb >> 1) & 3)) << 3;
      glds16(W + (size_t)rb * K + kt + swz, Bsb + (size_t)(h * 64 + w * 16) * BK);
    }
  };

  f32x4 acc[4][4];
  #pragma unroll
  for (int m = 0; m < 4; ++m)
    #pragma unroll
    for (int n = 0; n < 4; ++n) acc[m][n] = (f32x4){0.f, 0.f, 0.f, 0.f};

  // ---- prologue: stage k=0 into buf0 (no barrier; iter-0's counted wait covers it) ----
  stageA1(0, As0);
  stageB(W1, 0, Bs0);

  // ---- phase 1: h1 = [X;S] @ W1 (counted-vmcnt pipeline) ----
  int db = 0;
  for (int kt = 0; kt < K; kt += BK) {
    u16* AsN = db ? As0 : As1;
    u16* BsN = db ? Bs0 : Bs1;
    if (kt + BK < K) {
      stageA1(kt + BK, AsN);
      stageB(W1, kt + BK, BsN);
      asm volatile("s_waitcnt vmcnt(5)" ::: "memory");   // drain tile t only
    } else {
      stageB(W2, 0, BsN);                                // prefetch phase-3 first tile
      asm volatile("s_waitcnt vmcnt(4)" ::: "memory");
    }
    asm volatile("s_barrier" ::: "memory");
    const u16* Asb = db ? As1 : As0;
    const u16* Bsb = db ? Bs1 : Bs0;

    bf16x8 af[4], bfr[4];
    #pragma unroll
    for (int m = 0; m < 4; ++m) {
      int row = m * 16 + (lane & 15);
      int idx = (row << 5) + ((((lane >> 4) ^ ((row >> 1) & 3))) << 3);
      af[m] = *reinterpret_cast<const bf16x8*>(Asb + idx);
    }
    #pragma unroll
    for (int n = 0; n < 4; ++n) {
      int row = w * 64 + n * 16 + (lane & 15);
      int idx = (row << 5) + ((((lane >> 4) ^ ((row >> 1) & 3))) << 3);
      bfr[n] = *reinterpret_cast<const bf16x8*>(Bsb + idx);
    }
    #pragma unroll
    for (int m = 0; m < 4; ++m)
      #pragma unroll
      for (int n = 0; n < 4; ++n)
        acc[m][n] = __builtin_amdgcn_mfma_f32_16x16x32_bf16(af[m], bfr[n], acc[m][n], 0, 0, 0);
    asm volatile("s_barrier" ::: "memory");              // WAR seal, no drain
    db ^= 1;
  }

  // ---- phase 2: leaky(h1 + b1) -> slab (granule-swizzled bf16) ----
  #pragma unroll
  for (int n = 0; n < 4; ++n) {
    int c = w * 64 + n * 16 + (lane & 15);
    float b = b1[c];
    #pragma unroll
    for (int m = 0; m < 4; ++m) {
      #pragma unroll
      for (int r = 0; r < 4; ++r) {
        int row = m * 16 + ((lane >> 4) << 2) + r;
        float v = acc[m][n][r] + b;
        v = (v >= 0.f) ? v : 0.01f * v;
        int g = (c >> 3) ^ (row & 7);
        slab[row * 256 + g * 8 + (c & 7)] = f2bf(v);
        acc[m][n][r] = 0.f;
      }
    }
  }
  // slab visibility without draining the in-flight W2 prefetch (lgkm only)
  asm volatile("s_waitcnt lgkmcnt(0)\n\ts_barrier" ::: "memory");

  // ---- phase 3: [proj|self] = slab @ W2c (counted-vmcnt pipeline) ----
  for (int kt = 0; kt < K; kt += BK) {
    u16* BsN = db ? Bs0 : Bs1;
    if (kt + BK < K) {
      stageB(W2, kt + BK, BsN);
      asm volatile("s_waitcnt vmcnt(4)" ::: "memory");
    } else {
      asm volatile("s_waitcnt vmcnt(0)" ::: "memory");
    }
    asm volatile("s_barrier" ::: "memory");
    const u16* Bsb = db ? Bs1 : Bs0;

    bf16x8 af[4], bfr[4];
    #pragma unroll
    for (int m = 0; m < 4; ++m) {
      int row = m * 16 + (lane & 15);
      int g = ((kt >> 3) + (lane >> 4)) ^ (row & 7);
      af[m] = *reinterpret_cast<const bf16x8*>(slab + row * 256 + g * 8);
    }
    #pragma unroll
    for (int n = 0; n < 4; ++n) {
      int row = w * 64 + n * 16 + (lane & 15);
      int idx = (row << 5) + ((((lane >> 4) ^ ((row >> 1) & 3))) << 3);
      bfr[n] = *reinterpret_cast<const bf16x8*>(Bsb + idx);
    }
    #pragma unroll
    for (int m = 0; m < 4; ++m)
      #pragma unroll
      for (int n = 0; n < 4; ++n)
        acc[m][n] = __builtin_amdgcn_mfma_f32_16x16x32_bf16(af[m], bfr[n], acc[m][n], 0, 0, 0);
    asm volatile("s_barrier" ::: "memory");
    db ^= 1;
  }

  // ---- phase 4: epilogue via slab ----
  #pragma unroll
  for (int n = 0; n < 4; ++n) {
    int c = w * 64 + n * 16 + (lane & 15);
    float b = (c >= 128) ? b2[c - 128] : 0.f;
    #pragma unroll
    for (int m = 0; m < 4; ++m) {
      #pragma unroll
      for (int r = 0; r < 4; ++r) {
        int row = m * 16 + ((lane >> 4) << 2) + r;
        int g = (c >> 3) ^ (row & 7);
        slab[row * 256 + g * 8 + (c & 7)] = f2bf(acc[m][n][r] + b);
      }
    }
  }
  __syncthreads();
  #pragma unroll
  for (int p = 0; p < 8; ++p) {
    int chunk = p * 256 + tid;
    int row = chunk >> 5;            // 0..63
    int gg  = chunk & 31;            // output granule (8 cols)
    int G = gr0 + row;
    if (G < M) {
      int gsw = gg ^ (row & 7);
      u16x8 v = *reinterpret_cast<const u16x8*>(slab + row * 256 + gsw * 8);
      int col = gg * 8;
      if (col < 128)
        *reinterpret_cast<u16x8*>(proj + (size_t)G * 128 + col) = v;          // cached
      else
        __builtin_nontemporal_store(v,
            reinterpret_cast<u16x8*>(selfp + (size_t)G * 128 + (col - 128))); // streaming
    }
  }
}

// ==================== launch ====================
extern "C" void kernel_launch(void* const* d_in, const int* in_sizes, int n_in,
                              void* d_out, int out_size, void* d_ws, size_t ws_size,
                              hipStream_t stream) {
  const float* emb_user    = (const float*)d_in[0];
  const float* emb_item    = (const float*)d_in[1];
  const float* W1_self_ui  = (const float*)d_in[2];
  const float* W1_neigh_ui = (const float*)d_in[3];
  const float* b1_ui       = (const float*)d_in[4];
  const float* W1_self_iu  = (const float*)d_in[5];
  const float* W1_neigh_iu = (const float*)d_in[6];
  const float* b1_iu       = (const float*)d_in[7];
  const float* W2_self_ui  = (const float*)d_in[8];
  const float* W2_neigh_ui = (const float*)d_in[9];
  const float* b2_ui       = (const float*)d_in[10];
  const float* W2_self_iu  = (const float*)d_in[11];
  const float* W2_neigh_iu = (const float*)d_in[12];
  const float* b2_iu       = (const float*)d_in[13];
  const int* e1_src = (const int*)d_in[14];
  const int* e1_dst = (const int*)d_in[15];
  const int* e2_src = (const int*)d_in[16];
  const int* e2_dst = (const int*)d_in[17];

  // ---- workspace ----
  u16* p16 = (u16*)d_ws;
  u16* ue       = p16; p16 += (size_t)NUc * 128;
  u16* ie       = p16; p16 += (size_t)NIc * 128;
  u16* aggb_i   = p16; p16 += (size_t)NIc * 128;
  u16* aggb_u   = p16; p16 += (size_t)NUc * 128;
  u16* proj_u2i = p16; p16 += (size_t)NUc * 128;
  u16* self_u   = p16; p16 += (size_t)NUc * 128;
  u16* proj_i2u = p16; p16 += (size_t)NIc * 128;
  u16* self_i   = p16; p16 += (size_t)NIc * 128;
  u16* Wt1_ui   = p16; p16 += 256 * 256;
  u16* Wt1_iu   = p16; p16 += 256 * 256;
  u16* Wt2c_u   = p16; p16 += 256 * 256;
  u16* Wt2c_i   = p16; p16 += 256 * 256;
  int* ip    = (int*)p16;
  int* ideg1 = ip;  ip += NIc;
  int* ideg2 = ip;  ip += NUc;
  int* off1  = ip;  ip += NIc + 1;
  int* off2  = ip;  ip += NUc + 1;
  int* rank1 = ip;  ip += Ec;
  int* rank2 = ip;  ip += Ec;
  int* csr1  = ip;  ip += Ec;
  int* csr2  = ip;  ip += Ec;
  int* bsum1 = ip;  ip += 512;
  int* bscan1= ip;  ip += 512;
  int* bsum2 = ip;  ip += 512;
  int* bscan2= ip;  ip += 512;

  float* h2_user = (float*)d_out;
  float* h2_item = h2_user + (size_t)NUc * 128;

  dim3 blk(256);
  const int gatherBlocks = 2 * ((100000 + 63) / 64);   // 3126
  dim3 fusedGrid((100000 + 63) / 64, 1, 2);            // 1563 x 2

  // ---- CSR build + prep ----
  hipMemsetAsync(ideg1, 0, sizeof(int) * (size_t)(NIc + NUc), stream);
  hist_kernel<<<1024, blk, 0, stream>>>(e1_dst, e2_dst, ideg1, ideg2, rank1, rank2);
  prep_cast<<<PREP_B, blk, 0, stream>>>(
      emb_user, emb_item,
      W1_self_ui, W1_neigh_ui, W1_self_iu, W1_neigh_iu,
      W2_self_ui, W2_neigh_ui, W2_self_iu, W2_neigh_iu,
      ue, ie, Wt1_ui, Wt1_iu, Wt2c_u, Wt2c_i);
  block_reduce2<<<dim3(NB, 2), blk, 0, stream>>>(ideg1, ideg2, bsum1, bsum2, NIc);
  scan_bsums2<<<2, 512, 0, stream>>>(bsum1, bsum2, bscan1, bscan2, NB);
  scan_blocks2<<<dim3(NB, 2), blk, 0, stream>>>(ideg1, ideg2, bscan1, bscan2, off1, off2, NIc);
  fill_csr_kernel<<<1024, blk, 0, stream>>>(e1_src, e1_dst, e2_src, e2_dst,
                                            rank1, rank2, off1, off2, csr1, csr2);

  // ---- layer 1 gather ----
  gather_blk<0><<<gatherBlocks, blk, 0, stream>>>(
      ue, off1, csr1, nullptr, aggb_i,
      ie, off2, csr2, nullptr, aggb_u);

  // ---- fused L1+L2 GEMM (h1 stays on-chip) ----
  fused_gemm<<<fusedGrid, blk, 0, stream>>>(
      ie, aggb_i, Wt1_ui, b1_ui, Wt2c_i, b2_ui, proj_i2u, self_i,
      ue, aggb_u, Wt1_iu, b1_iu, Wt2c_u, b2_iu, proj_u2i, self_u, Mrows);

  // ---- layer 2 gather + final add -> f32 outputs ----
  gather_blk<1><<<gatherBlocks, blk, 0, stream>>>(
      proj_u2i, off1, csr1, self_i, h2_item,
      proj_i2u, off2, csr2, self_u, h2_user);
}